// Round 1
// baseline (706.567 us; speedup 1.0000x reference)
//
#include <hip/hip_runtime.h>
#include <math.h>

namespace {
constexpr int kB = 32;
constexpr int kN = 100000;
constexpr int kL = 12;
constexpr int kS = 256;
constexpr int kBG = 8;                      // poses per block in deform kernel
constexpr int kNB = (kN + 255) / 256;       // 391 atom-blocks

constexpr float kGauss = (float)(2.0 * M_PI * M_PI);                         // 2(pi*sigma)^2, sigma=1
constexpr float kA1 = (float)(M_PI * 0.0197);                                // pi*lambda
constexpr float kA2 = (float)(0.5 * M_PI * 2.7e7 * 0.0197 * 0.0197 * 0.0197);// 0.5*pi*Cs*lambda^3
constexpr float kW1 = 0.99498743710661995f;                                  // sqrt(1-Q0^2)
constexpr float kQ0 = 0.1f;
}

// ---------------------------------------------------------------------------
// 256-point Stockham radix-2 FFT in LDS. 128 lanes per FFT, 8 stages,
// auto-sorting (no bit reversal). Result ends in the buffer passed as `a`.
// Contains __syncthreads(): must be called by all 256 threads of the block.
// ---------------------------------------------------------------------------
__device__ __forceinline__ float2* fft256(float2* a, float2* b, int lane, float sign) {
#pragma unroll
  for (int m = 1; m <= 128; m <<= 1) {
    float2 c0 = a[lane];
    float2 c1 = a[lane + 128];
    int jm = lane & ~(m - 1);
    float ang = sign * 0.0245436926061703f * (float)jm;  // pi/128 * jm
    float s, c;
    __sincosf(ang, &s, &c);
    float ex = c0.x + c1.x, ey = c0.y + c1.y;
    float dx = c0.x - c1.x, dy = c0.y - c1.y;
    b[lane + jm]     = make_float2(ex, ey);
    b[lane + jm + m] = make_float2(c * dx - s * dy, c * dy + s * dx);
    __syncthreads();
    float2* t = a; a = b; b = t;
  }
  return a;  // 8 swaps -> result back in original `a` buffer
}

// ---------------------------------------------------------------------------
// Fused: deformation -> (bond, angle, projection, bilinear splat)
// block: 256 atoms, loops over kBG poses. grid: (391, B/kBG)
// ---------------------------------------------------------------------------
__global__ __launch_bounds__(256) void k_deform(
    const float* __restrict__ c_nma, const float* __restrict__ delta_euler,
    const float* __restrict__ delta_shifts, const float* __restrict__ coords,
    const float* __restrict__ basis_x, const float* __restrict__ basis_y,
    const float* __restrict__ basis_z, const float* __restrict__ euler_base,
    const float* __restrict__ shifts_base,
    float* __restrict__ img, float* __restrict__ bond, float* __restrict__ angle) {
  __shared__ float cn_s[kBG][kL];
  __shared__ float rsh_s[kBG][8];
  __shared__ float pt[258][3];

  const int t = threadIdx.x;
  const int n0 = blockIdx.x * 256;
  const int bg = blockIdx.y * kBG;

  if (t < kBG * kL) cn_s[t / kL][t % kL] = c_nma[(bg + t / kL) * kL + (t % kL)];
  if (t < kBG) {
    int b = bg + t;
    float rot  = euler_base[b * 3 + 0] + delta_euler[b * 3 + 0];
    float tilt = euler_base[b * 3 + 1] + delta_euler[b * 3 + 1];
    float psi  = euler_base[b * 3 + 2] + delta_euler[b * 3 + 2];
    float ca = cosf(rot), sa = sinf(rot);
    float cb = cosf(tilt), sb = sinf(tilt);
    float cg = cosf(psi), sg = sinf(psi);
    rsh_s[t][0] = cg * cb * ca - sg * sa;
    rsh_s[t][1] = cg * cb * sa + sg * ca;
    rsh_s[t][2] = -cg * sb;
    rsh_s[t][3] = -sg * cb * ca - cg * sa;
    rsh_s[t][4] = -sg * cb * sa + cg * ca;
    rsh_s[t][5] = sg * sb;
    rsh_s[t][6] = shifts_base[b * 2 + 0] + delta_shifts[b * 2 + 0] + 128.0f;
    rsh_s[t][7] = shifts_base[b * 2 + 1] + delta_shifts[b * 2 + 1] + 128.0f;
  }

  const int n = n0 + t;
  const bool valid = n < kN;
  float cx = 0.f, cy = 0.f, cz = 0.f;
  float bx[kL], by[kL], bz[kL];
#pragma unroll
  for (int l = 0; l < kL; ++l) { bx[l] = 0.f; by[l] = 0.f; bz[l] = 0.f; }
  if (valid) {
    cx = coords[n * 3 + 0]; cy = coords[n * 3 + 1]; cz = coords[n * 3 + 2];
    const float4* px4 = reinterpret_cast<const float4*>(basis_x + (size_t)n * kL);
    const float4* py4 = reinterpret_cast<const float4*>(basis_y + (size_t)n * kL);
    const float4* pz4 = reinterpret_cast<const float4*>(basis_z + (size_t)n * kL);
#pragma unroll
    for (int q = 0; q < 3; ++q) {
      float4 vx = px4[q], vy = py4[q], vz = pz4[q];
      bx[q * 4 + 0] = vx.x; bx[q * 4 + 1] = vx.y; bx[q * 4 + 2] = vx.z; bx[q * 4 + 3] = vx.w;
      by[q * 4 + 0] = vy.x; by[q * 4 + 1] = vy.y; by[q * 4 + 2] = vy.z; by[q * 4 + 3] = vy.w;
      bz[q * 4 + 0] = vz.x; bz[q * 4 + 1] = vz.y; bz[q * 4 + 2] = vz.z; bz[q * 4 + 3] = vz.w;
    }
  }
  __syncthreads();

  for (int bi = 0; bi < kBG; ++bi) {
    const int b = bg + bi;
    float px = cx, py = cy, pz = cz;
#pragma unroll
    for (int l = 0; l < kL; ++l) {
      float cc = cn_s[bi][l];
      px = fmaf(cc, bx[l], px);
      py = fmaf(cc, by[l], py);
      pz = fmaf(cc, bz[l], pz);
    }
    if (valid) { pt[t][0] = px; pt[t][1] = py; pt[t][2] = pz; }
    if (t < 2) {  // halo: atoms n0+256, n0+257 for bond/angle neighbors
      int nh = n0 + 256 + t;
      if (nh < kN) {
        float hx = coords[nh * 3 + 0], hy = coords[nh * 3 + 1], hz = coords[nh * 3 + 2];
        const float* hbx = basis_x + (size_t)nh * kL;
        const float* hby = basis_y + (size_t)nh * kL;
        const float* hbz = basis_z + (size_t)nh * kL;
#pragma unroll
        for (int l = 0; l < kL; ++l) {
          float cc = cn_s[bi][l];
          hx = fmaf(cc, hbx[l], hx);
          hy = fmaf(cc, hby[l], hy);
          hz = fmaf(cc, hbz[l], hz);
        }
        pt[256 + t][0] = hx; pt[256 + t][1] = hy; pt[256 + t][2] = hz;
      }
    }
    __syncthreads();
    if (valid) {
      // projection + bilinear splat
      float xr = fmaf(rsh_s[bi][0], px, fmaf(rsh_s[bi][1], py, fmaf(rsh_s[bi][2], pz, rsh_s[bi][6])));
      float yr = fmaf(rsh_s[bi][3], px, fmaf(rsh_s[bi][4], py, fmaf(rsh_s[bi][5], pz, rsh_s[bi][7])));
      xr = fminf(fmaxf(xr, 0.0f), 254.999f);
      yr = fminf(fmaxf(yr, 0.0f), 254.999f);
      int x0 = (int)xr, y0 = (int)yr;
      float fx = xr - (float)x0, fy = yr - (float)y0;
      float* ib = img + ((size_t)b * kS + y0) * kS + x0;
      unsafeAtomicAdd(ib,          (1.f - fx) * (1.f - fy));
      unsafeAtomicAdd(ib + 1,      fx * (1.f - fy));
      unsafeAtomicAdd(ib + kS,     (1.f - fx) * fy);
      unsafeAtomicAdd(ib + kS + 1, fx * fy);
      // bond length
      if (n < kN - 1) {
        float dx = pt[t + 1][0] - px, dy = pt[t + 1][1] - py, dz = pt[t + 1][2] - pz;
        bond[(size_t)b * (kN - 1) + n] =
            sqrtf(fmaf(dx, dx, fmaf(dy, dy, fmaf(dz, dz, 1e-12f))));
      }
      // angle at interior atom n+1
      if (n < kN - 2) {
        float mx = pt[t + 1][0], my = pt[t + 1][1], mz = pt[t + 1][2];
        float ux = px - mx, uy = py - my, uz = pz - mz;
        float vx = pt[t + 2][0] - mx, vy = pt[t + 2][1] - my, vz = pt[t + 2][2] - mz;
        float uu = ux * ux + uy * uy + uz * uz;
        float vv = vx * vx + vy * vy + vz * vz;
        float uv = ux * vx + uy * vy + uz * vz;
        float cosang = uv / (sqrtf(uu) * sqrtf(vv) + 1e-12f);
        cosang = fminf(fmaxf(cosang, -0.9999f), 0.9999f);
        angle[(size_t)b * (kN - 2) + n] = acosf(cosang);
      }
    }
    __syncthreads();
  }
}

// ---------------------------------------------------------------------------
// FFT passes: rows forward (real->complex), cols (fwd FFT * H * inv FFT),
// rows inverse (complex->real, 1/65536 normalization).
// ---------------------------------------------------------------------------
__global__ __launch_bounds__(256) void k_fft_rows_fwd(const float* __restrict__ img,
                                                      float2* __restrict__ Fc) {
  __shared__ float2 sm[4][256];
  const int t = threadIdx.x, half = t >> 7, lane = t & 127;
  const int r = blockIdx.x * 2 + half;  // [0, B*256)
  const float* row = img + (size_t)r * kS;
  float2* a = sm[half * 2];
  float2* b = sm[half * 2 + 1];
  a[lane]       = make_float2(row[lane], 0.f);
  a[lane + 128] = make_float2(row[lane + 128], 0.f);
  float2* res = fft256(a, b, lane, -1.f);
  float2* o = Fc + (size_t)r * kS;
  o[lane]       = res[lane];
  o[lane + 128] = res[lane + 128];
}

__global__ __launch_bounds__(256) void k_fft_cols(float2* __restrict__ Fc,
                                                  const float* __restrict__ defocus) {
  __shared__ float2 sm[4][256];
  const int t = threadIdx.x, half = t >> 7, lane = t & 127;
  const int c = blockIdx.x * 2 + half;  // [0, B*256)
  const int b = c >> 8, kx = c & 255;
  float2* col = Fc + (size_t)b * kS * kS + kx;
  float2* a = sm[half * 2];
  float2* bb = sm[half * 2 + 1];
  a[lane]       = col[(size_t)lane * kS];
  a[lane + 128] = col[(size_t)(lane + 128) * kS];
  float2* r1 = fft256(a, bb, lane, -1.f);

  // apply real filter H(ky,kx) = G * CTF  (defocus-dependent per pose)
  const float D = defocus[b];
  const float fxv = (float)(kx < 128 ? kx : kx - 256) * (1.0f / 256.0f);
  const float fx2 = fxv * fxv;
#pragma unroll
  for (int h = 0; h < 2; ++h) {
    int ky = lane + h * 128;
    float fyv = (float)(ky < 128 ? ky : ky - 256) * (1.0f / 256.0f);
    float s2 = fyv * fyv + fx2;
    float G = __expf(-kGauss * s2);
    float chi = kA1 * D * s2 - kA2 * s2 * s2;
    float sn, cn;
    sincosf(chi, &sn, &cn);
    float H = G * (-(kW1 * sn + kQ0 * cn));
    r1[ky].x *= H;
    r1[ky].y *= H;
  }
  float2* r2 = (r1 == a) ? bb : a;
  float2* res = fft256(r1, r2, lane, 1.f);
  col[(size_t)lane * kS]         = res[lane];
  col[(size_t)(lane + 128) * kS] = res[lane + 128];
}

__global__ __launch_bounds__(256) void k_fft_rows_inv(const float2* __restrict__ Fc,
                                                      float* __restrict__ out) {
  __shared__ float2 sm[4][256];
  const int t = threadIdx.x, half = t >> 7, lane = t & 127;
  const int r = blockIdx.x * 2 + half;
  const float2* row = Fc + (size_t)r * kS;
  float2* a = sm[half * 2];
  float2* b = sm[half * 2 + 1];
  a[lane]       = row[lane];
  a[lane + 128] = row[lane + 128];
  float2* res = fft256(a, b, lane, 1.f);
  out[(size_t)r * kS + lane]       = res[lane].x * (1.0f / 65536.0f);
  out[(size_t)r * kS + lane + 128] = res[lane + 128].x * (1.0f / 65536.0f);
}

// ---------------------------------------------------------------------------
extern "C" void kernel_launch(void* const* d_in, const int* in_sizes, int n_in,
                              void* d_out, int out_size, void* d_ws, size_t ws_size,
                              hipStream_t stream) {
  const float* c_nma        = (const float*)d_in[0];
  const float* delta_euler  = (const float*)d_in[1];
  const float* delta_shifts = (const float*)d_in[2];
  const float* coords       = (const float*)d_in[3];
  const float* basis_x      = (const float*)d_in[4];
  const float* basis_y      = (const float*)d_in[5];
  const float* basis_z      = (const float*)d_in[6];
  const float* euler_base   = (const float*)d_in[7];
  const float* shifts_base  = (const float*)d_in[8];
  const float* defocus      = (const float*)d_in[9];

  float* out = (float*)d_out;
  float* decoded = out;                                   // B*S*S
  float* bond    = out + (size_t)kB * kS * kS;            // B*(N-1)
  float* angle   = bond + (size_t)kB * (kN - 1);          // B*(N-2)

  char* ws = (char*)d_ws;
  float*  img = (float*)ws;                               // B*S*S floats (8 MB)
  float2* Fc  = (float2*)(ws + (size_t)kB * kS * kS * 4); // B*S*S float2 (16.8 MB)

  hipMemsetAsync(img, 0, (size_t)kB * kS * kS * sizeof(float), stream);

  dim3 gd(kNB, kB / kBG);
  k_deform<<<gd, 256, 0, stream>>>(c_nma, delta_euler, delta_shifts, coords,
                                   basis_x, basis_y, basis_z, euler_base,
                                   shifts_base, img, bond, angle);
  k_fft_rows_fwd<<<kB * kS / 2, 256, 0, stream>>>(img, Fc);
  k_fft_cols<<<kB * kS / 2, 256, 0, stream>>>(Fc, defocus);
  k_fft_rows_inv<<<kB * kS / 2, 256, 0, stream>>>(Fc, decoded);
}

// Round 2
// 247.770 us; speedup vs baseline: 2.8517x; 2.8517x over previous
//
#include <hip/hip_runtime.h>
#include <math.h>

namespace {
constexpr int kB = 32;
constexpr int kN = 100000;
constexpr int kL = 12;
constexpr int kS = 256;
constexpr int kBG = 8;                      // poses per block in deform kernel
constexpr int kNB = (kN + 255) / 256;       // 391 atom-blocks

constexpr float kGauss = (float)(2.0 * M_PI * M_PI);                         // 2(pi*sigma)^2, sigma=1
constexpr float kA1 = (float)(M_PI * 0.0197);                                // pi*lambda
constexpr float kA2 = (float)(0.5 * M_PI * 2.7e7 * 0.0197 * 0.0197 * 0.0197);// 0.5*pi*Cs*lambda^3
constexpr float kW1 = 0.99498743710661995f;                                  // sqrt(1-Q0^2)
constexpr float kQ0 = 0.1f;
}

// ---------------------------------------------------------------------------
// 256-point Stockham radix-2 FFT in LDS with a shared twiddle table.
// 128 lanes per FFT, 8 stages, auto-sorting. Result ends in buffer `a`.
// tw[k] = (cos, sin)(pi*k/128); SIGN=-1 forward, +1 inverse.
// Contains __syncthreads(): all 256 threads of the block must call uniformly.
// ---------------------------------------------------------------------------
template <int SIGN>
__device__ __forceinline__ float2* fft256t(float2* a, float2* b, int lane,
                                           const float2* tw) {
#pragma unroll
  for (int m = 1; m <= 128; m <<= 1) {
    float2 c0 = a[lane];
    float2 c1 = a[lane + 128];
    int jm = lane & ~(m - 1);
    float2 w = tw[jm];
    float c = w.x;
    float s = (SIGN < 0) ? -w.y : w.y;
    float ex = c0.x + c1.x, ey = c0.y + c1.y;
    float dx = c0.x - c1.x, dy = c0.y - c1.y;
    b[lane + jm]     = make_float2(ex, ey);
    b[lane + jm + m] = make_float2(c * dx - s * dy, c * dy + s * dx);
    __syncthreads();
    float2* tp = a; a = b; b = tp;
  }
  return a;  // 8 swaps -> result back in original `a` buffer
}

__device__ __forceinline__ void build_tw(float2* tw, int t) {
  if (t < 128) {
    float s, c;
    sincosf((float)M_PI / 128.0f * (float)t, &s, &c);
    tw[t] = make_float2(c, s);
  }
}

// ---------------------------------------------------------------------------
// Phase A: deformation -> bond, angle, projected (x,y) as packed u16.8 fixed pt
// block: 256 atoms, loops over kBG poses. grid: (391, B/kBG). NO atomics.
// ---------------------------------------------------------------------------
__global__ __launch_bounds__(256) void k_deform(
    const float* __restrict__ c_nma, const float* __restrict__ delta_euler,
    const float* __restrict__ delta_shifts, const float* __restrict__ coords,
    const float* __restrict__ basis_x, const float* __restrict__ basis_y,
    const float* __restrict__ basis_z, const float* __restrict__ euler_base,
    const float* __restrict__ shifts_base,
    unsigned* __restrict__ xy, float* __restrict__ bond, float* __restrict__ angle) {
  __shared__ float cn_s[kBG][kL];
  __shared__ float rsh_s[kBG][8];
  __shared__ float pt[258][3];

  const int t = threadIdx.x;
  const int n0 = blockIdx.x * 256;
  const int bg = blockIdx.y * kBG;

  if (t < kBG * kL) cn_s[t / kL][t % kL] = c_nma[(bg + t / kL) * kL + (t % kL)];
  if (t < kBG) {
    int b = bg + t;
    float rot  = euler_base[b * 3 + 0] + delta_euler[b * 3 + 0];
    float tilt = euler_base[b * 3 + 1] + delta_euler[b * 3 + 1];
    float psi  = euler_base[b * 3 + 2] + delta_euler[b * 3 + 2];
    float ca = cosf(rot), sa = sinf(rot);
    float cb = cosf(tilt), sb = sinf(tilt);
    float cg = cosf(psi), sg = sinf(psi);
    rsh_s[t][0] = cg * cb * ca - sg * sa;
    rsh_s[t][1] = cg * cb * sa + sg * ca;
    rsh_s[t][2] = -cg * sb;
    rsh_s[t][3] = -sg * cb * ca - cg * sa;
    rsh_s[t][4] = -sg * cb * sa + cg * ca;
    rsh_s[t][5] = sg * sb;
    rsh_s[t][6] = shifts_base[b * 2 + 0] + delta_shifts[b * 2 + 0] + 128.0f;
    rsh_s[t][7] = shifts_base[b * 2 + 1] + delta_shifts[b * 2 + 1] + 128.0f;
  }

  const int n = n0 + t;
  const bool valid = n < kN;
  float cx = 0.f, cy = 0.f, cz = 0.f;
  float bx[kL], by[kL], bz[kL];
#pragma unroll
  for (int l = 0; l < kL; ++l) { bx[l] = 0.f; by[l] = 0.f; bz[l] = 0.f; }
  if (valid) {
    cx = coords[n * 3 + 0]; cy = coords[n * 3 + 1]; cz = coords[n * 3 + 2];
    const float4* px4 = reinterpret_cast<const float4*>(basis_x + (size_t)n * kL);
    const float4* py4 = reinterpret_cast<const float4*>(basis_y + (size_t)n * kL);
    const float4* pz4 = reinterpret_cast<const float4*>(basis_z + (size_t)n * kL);
#pragma unroll
    for (int q = 0; q < 3; ++q) {
      float4 vx = px4[q], vy = py4[q], vz = pz4[q];
      bx[q * 4 + 0] = vx.x; bx[q * 4 + 1] = vx.y; bx[q * 4 + 2] = vx.z; bx[q * 4 + 3] = vx.w;
      by[q * 4 + 0] = vy.x; by[q * 4 + 1] = vy.y; by[q * 4 + 2] = vy.z; by[q * 4 + 3] = vy.w;
      bz[q * 4 + 0] = vz.x; bz[q * 4 + 1] = vz.y; bz[q * 4 + 2] = vz.z; bz[q * 4 + 3] = vz.w;
    }
  }
  __syncthreads();

  for (int bi = 0; bi < kBG; ++bi) {
    const int b = bg + bi;
    float px = cx, py = cy, pz = cz;
#pragma unroll
    for (int l = 0; l < kL; ++l) {
      float cc = cn_s[bi][l];
      px = fmaf(cc, bx[l], px);
      py = fmaf(cc, by[l], py);
      pz = fmaf(cc, bz[l], pz);
    }
    if (valid) { pt[t][0] = px; pt[t][1] = py; pt[t][2] = pz; }
    if (t < 2) {  // halo: atoms n0+256, n0+257 for bond/angle neighbors
      int nh = n0 + 256 + t;
      if (nh < kN) {
        float hx = coords[nh * 3 + 0], hy = coords[nh * 3 + 1], hz = coords[nh * 3 + 2];
        const float* hbx = basis_x + (size_t)nh * kL;
        const float* hby = basis_y + (size_t)nh * kL;
        const float* hbz = basis_z + (size_t)nh * kL;
#pragma unroll
        for (int l = 0; l < kL; ++l) {
          float cc = cn_s[bi][l];
          hx = fmaf(cc, hbx[l], hx);
          hy = fmaf(cc, hby[l], hy);
          hz = fmaf(cc, hbz[l], hz);
        }
        pt[256 + t][0] = hx; pt[256 + t][1] = hy; pt[256 + t][2] = hz;
      }
    }
    __syncthreads();
    if (valid) {
      // projection; quantize to u16.8 fixed point (floor), pack (y<<16)|x
      float xr = fmaf(rsh_s[bi][0], px, fmaf(rsh_s[bi][1], py, fmaf(rsh_s[bi][2], pz, rsh_s[bi][6])));
      float yr = fmaf(rsh_s[bi][3], px, fmaf(rsh_s[bi][4], py, fmaf(rsh_s[bi][5], pz, rsh_s[bi][7])));
      xr = fminf(fmaxf(xr, 0.0f), 254.999f);
      yr = fminf(fmaxf(yr, 0.0f), 254.999f);
      unsigned xf = (unsigned)(xr * 256.0f);   // <= 65279 -> x0 <= 254
      unsigned yf = (unsigned)(yr * 256.0f);
      xy[(size_t)b * kN + n] = (yf << 16) | xf;
      // bond length
      if (n < kN - 1) {
        float dx = pt[t + 1][0] - px, dy = pt[t + 1][1] - py, dz = pt[t + 1][2] - pz;
        bond[(size_t)b * (kN - 1) + n] =
            sqrtf(fmaf(dx, dx, fmaf(dy, dy, fmaf(dz, dz, 1e-12f))));
      }
      // angle at interior atom n+1
      if (n < kN - 2) {
        float mx = pt[t + 1][0], my = pt[t + 1][1], mz = pt[t + 1][2];
        float ux = px - mx, uy = py - my, uz = pz - mz;
        float vx = pt[t + 2][0] - mx, vy = pt[t + 2][1] - my, vz = pt[t + 2][2] - mz;
        float uu = ux * ux + uy * uy + uz * uz;
        float vv = vx * vx + vy * vy + vz * vz;
        float uv = ux * vx + uy * vy + uz * vz;
        float cosang = uv / (sqrtf(uu) * sqrtf(vv) + 1e-12f);
        cosang = fminf(fmaxf(cosang, -0.9999f), 0.9999f);
        angle[(size_t)b * (kN - 2) + n] = acosf(cosang);
      }
    }
    __syncthreads();
  }
}

// ---------------------------------------------------------------------------
// Phase B: bilinear splat via LDS tile accumulation.
// One block per (pose, 32-row band): scans the pose's full xy list, LDS-atomic
// accumulates atoms in band into a 33x256 tile, writes out with plain stores
// (boundary rows 0 and 32 via global atomics -- shared with adjacent bands).
// grid: 32 poses * 8 bands = 256 blocks.
// ---------------------------------------------------------------------------
__global__ __launch_bounds__(256) void k_splat(const unsigned* __restrict__ xy,
                                               float* __restrict__ img) {
  __shared__ float tile[33 * 256];
  const int t = threadIdx.x;
  const int b = blockIdx.x >> 3;
  const int band = blockIdx.x & 7;
  const int r0 = band * 32;
#pragma unroll
  for (int i = 0; i < 33; ++i) tile[i * 256 + t] = 0.f;
  __syncthreads();

  const uint4* xy4 = reinterpret_cast<const uint4*>(xy + (size_t)b * kN);
  for (int i = t; i < kN / 4; i += 256) {
    uint4 u4 = xy4[i];
    unsigned us[4] = {u4.x, u4.y, u4.z, u4.w};
#pragma unroll
    for (int j = 0; j < 4; ++j) {
      unsigned u = us[j];
      int yf = (int)(u >> 16);
      int ry = (yf >> 8) - r0;
      if ((unsigned)ry < 32u) {
        int xf = (int)(u & 0xFFFFu);
        int x0 = xf >> 8;
        float fx = (float)(xf & 255) * (1.0f / 256.0f);
        float fy = (float)(yf & 255) * (1.0f / 256.0f);
        float* tb = tile + ry * 256 + x0;
        atomicAdd(tb,       (1.f - fx) * (1.f - fy));
        atomicAdd(tb + 1,   fx * (1.f - fy));
        atomicAdd(tb + 256, (1.f - fx) * fy);
        atomicAdd(tb + 257, fx * fy);
      }
    }
  }
  __syncthreads();

  float* ib = img + ((size_t)b * kS + r0) * kS + t;
#pragma unroll
  for (int r = 0; r < 33; ++r) {
    int row = r0 + r;
    if (row >= kS) break;                       // band 7 has no row 256
    float v = tile[r * 256 + t];
    if (r == 0 || r == 32) unsafeAtomicAdd(ib + (size_t)r * kS, v);
    else                   ib[(size_t)r * kS] = v;
  }
}

// ---------------------------------------------------------------------------
// FFT passes. Spectrum lives TRANSPOSED: FcT[b][kx][ky] so the column pass is
// fully coalesced; row passes transpose via LDS in 32B chunks.
// ---------------------------------------------------------------------------
__global__ __launch_bounds__(256) void k_fft_rows_fwd(const float* __restrict__ img,
                                                      float2* __restrict__ FcT) {
  __shared__ float2 smres[4][256];
  __shared__ float2 smtmp[2][256];
  __shared__ float2 tw[128];
  const int t = threadIdx.x, half = t >> 7, lane = t & 127;
  build_tw(tw, t);
  const int b = blockIdx.x >> 6;
  const int y0 = (blockIdx.x & 63) * 4;
  __syncthreads();
#pragma unroll
  for (int q = 0; q < 2; ++q) {
    int j = q * 2 + half;
    const float* row = img + ((size_t)b * kS + y0 + j) * kS;
    float2* a = smres[j];
    a[lane]       = make_float2(row[lane], 0.f);
    a[lane + 128] = make_float2(row[lane + 128], 0.f);
    fft256t<-1>(a, smtmp[half], lane, tw);
  }
  // transpose write: thread t = kx, 4 consecutive ky -> 32B contiguous
  float2 v0 = smres[0][t], v1 = smres[1][t], v2 = smres[2][t], v3 = smres[3][t];
  float4* o = reinterpret_cast<float4*>(FcT + ((size_t)b * kS + t) * kS + y0);
  o[0] = make_float4(v0.x, v0.y, v1.x, v1.y);
  o[1] = make_float4(v2.x, v2.y, v3.x, v3.y);
}

__global__ __launch_bounds__(256) void k_fft_cols(float2* __restrict__ FcT,
                                                  const float* __restrict__ defocus) {
  __shared__ float2 sm[4][256];
  __shared__ float2 tw[128];
  const int t = threadIdx.x, half = t >> 7, lane = t & 127;
  build_tw(tw, t);
  const int c = blockIdx.x * 2 + half;  // global column id in [0, B*256)
  const int b = c >> 8, kx = c & 255;
  float2* col = FcT + (size_t)c * kS;   // contiguous column
  float2* a = sm[half * 2];
  float2* bb = sm[half * 2 + 1];
  __syncthreads();
  a[lane]       = col[lane];
  a[lane + 128] = col[lane + 128];
  float2* r1 = fft256t<-1>(a, bb, lane, tw);

  // apply real filter H(ky,kx) = G * CTF (defocus-dependent per pose)
  const float D = defocus[b];
  const float fxv = (float)(kx < 128 ? kx : kx - 256) * (1.0f / 256.0f);
  const float fx2 = fxv * fxv;
#pragma unroll
  for (int h = 0; h < 2; ++h) {
    int ky = lane + h * 128;
    float fyv = (float)(ky < 128 ? ky : ky - 256) * (1.0f / 256.0f);
    float s2 = fyv * fyv + fx2;
    float G = __expf(-kGauss * s2);
    float chi = kA1 * D * s2 - kA2 * s2 * s2;
    float sn, cn;
    sincosf(chi, &sn, &cn);
    float H = G * (-(kW1 * sn + kQ0 * cn));
    r1[ky].x *= H;
    r1[ky].y *= H;
  }
  float2* r2 = (r1 == a) ? bb : a;
  float2* res = fft256t<1>(r1, r2, lane, tw);
  col[lane]       = res[lane];
  col[lane + 128] = res[lane + 128];
}

__global__ __launch_bounds__(256) void k_fft_rows_inv(const float2* __restrict__ FcT,
                                                      float* __restrict__ out) {
  __shared__ float2 smres[4][256];
  __shared__ float2 smtmp[2][256];
  __shared__ float2 tw[128];
  const int t = threadIdx.x, half = t >> 7, lane = t & 127;
  build_tw(tw, t);
  const int b = blockIdx.x >> 6;
  const int ky0 = (blockIdx.x & 63) * 4;
  // transpose read: thread t = kx, 4 consecutive ky = 32B contiguous
  const float4* ip = reinterpret_cast<const float4*>(FcT + ((size_t)b * kS + t) * kS + ky0);
  float4 w0 = ip[0], w1 = ip[1];
  smres[0][t] = make_float2(w0.x, w0.y);
  smres[1][t] = make_float2(w0.z, w0.w);
  smres[2][t] = make_float2(w1.x, w1.y);
  smres[3][t] = make_float2(w1.z, w1.w);
  __syncthreads();
#pragma unroll
  for (int q = 0; q < 2; ++q) {
    int j = q * 2 + half;
    float2* res = fft256t<1>(smres[j], smtmp[half], lane, tw);
    float* orow = out + ((size_t)b * kS + ky0 + j) * kS;
    orow[lane]       = res[lane].x * (1.0f / 65536.0f);
    orow[lane + 128] = res[lane + 128].x * (1.0f / 65536.0f);
  }
}

// ---------------------------------------------------------------------------
extern "C" void kernel_launch(void* const* d_in, const int* in_sizes, int n_in,
                              void* d_out, int out_size, void* d_ws, size_t ws_size,
                              hipStream_t stream) {
  const float* c_nma        = (const float*)d_in[0];
  const float* delta_euler  = (const float*)d_in[1];
  const float* delta_shifts = (const float*)d_in[2];
  const float* coords       = (const float*)d_in[3];
  const float* basis_x      = (const float*)d_in[4];
  const float* basis_y      = (const float*)d_in[5];
  const float* basis_z      = (const float*)d_in[6];
  const float* euler_base   = (const float*)d_in[7];
  const float* shifts_base  = (const float*)d_in[8];
  const float* defocus      = (const float*)d_in[9];

  float* out = (float*)d_out;
  float* decoded = out;                                   // B*S*S
  float* bond    = out + (size_t)kB * kS * kS;            // B*(N-1)
  float* angle   = bond + (size_t)kB * (kN - 1);          // B*(N-2)

  char* ws = (char*)d_ws;
  const size_t imgBytes = (size_t)kB * kS * kS * sizeof(float);  // 8 MB
  float*    img = (float*)ws;                      // [0, 8MB)
  unsigned* xy  = (unsigned*)(ws + imgBytes);      // [8MB, 20.8MB)  dead after k_splat
  float2*   FcT = (float2*)(ws + imgBytes);        // [8MB, 24.8MB)  aliases xy

  hipMemsetAsync(img, 0, imgBytes, stream);

  dim3 gd(kNB, kB / kBG);
  k_deform<<<gd, 256, 0, stream>>>(c_nma, delta_euler, delta_shifts, coords,
                                   basis_x, basis_y, basis_z, euler_base,
                                   shifts_base, xy, bond, angle);
  k_splat<<<kB * 8, 256, 0, stream>>>(xy, img);
  k_fft_rows_fwd<<<kB * 64, 256, 0, stream>>>(img, FcT);
  k_fft_cols<<<kB * kS / 2, 256, 0, stream>>>(FcT, defocus);
  k_fft_rows_inv<<<kB * 64, 256, 0, stream>>>(FcT, decoded);
}

// Round 3
// 247.240 us; speedup vs baseline: 2.8578x; 1.0021x over previous
//
#include <hip/hip_runtime.h>
#include <math.h>

namespace {
constexpr int kB = 32;
constexpr int kN = 100000;
constexpr int kL = 12;
constexpr int kS = 256;
constexpr int kBG = 8;                      // poses per block in deform kernel
constexpr int kNB = (kN + 255) / 256;       // 391 atom-blocks

constexpr float kGauss = (float)(2.0 * M_PI * M_PI);                         // 2(pi*sigma)^2, sigma=1
constexpr float kA1 = (float)(M_PI * 0.0197);                                // pi*lambda
constexpr float kA2 = (float)(0.5 * M_PI * 2.7e7 * 0.0197 * 0.0197 * 0.0197);// 0.5*pi*Cs*lambda^3
constexpr float kW1 = 0.99498743710661995f;                                  // sqrt(1-Q0^2)
constexpr float kQ0 = 0.1f;
}

// ---------------------------------------------------------------------------
// 256-point Stockham radix-2 FFT in LDS with a shared twiddle table.
// 128 lanes per FFT, 8 stages, auto-sorting. Result ends in buffer `a`.
// tw[k] = (cos, sin)(pi*k/128); SIGN=-1 forward, +1 inverse.
// Contains __syncthreads(): all 256 threads of the block must call uniformly.
// ---------------------------------------------------------------------------
template <int SIGN>
__device__ __forceinline__ float2* fft256t(float2* a, float2* b, int lane,
                                           const float2* tw) {
#pragma unroll
  for (int m = 1; m <= 128; m <<= 1) {
    float2 c0 = a[lane];
    float2 c1 = a[lane + 128];
    int jm = lane & ~(m - 1);
    float2 w = tw[jm];
    float c = w.x;
    float s = (SIGN < 0) ? -w.y : w.y;
    float ex = c0.x + c1.x, ey = c0.y + c1.y;
    float dx = c0.x - c1.x, dy = c0.y - c1.y;
    b[lane + jm]     = make_float2(ex, ey);
    b[lane + jm + m] = make_float2(c * dx - s * dy, c * dy + s * dx);
    __syncthreads();
    float2* tp = a; a = b; b = tp;
  }
  return a;  // 8 swaps -> result back in original `a` buffer
}

__device__ __forceinline__ void build_tw(float2* tw, int t) {
  if (t < 128) {
    float s, c;
    sincosf((float)M_PI / 128.0f * (float)t, &s, &c);
    tw[t] = make_float2(c, s);
  }
}

// ---------------------------------------------------------------------------
// Phase A: deformation -> bond, angle, projected (x,y) as packed u16.8 fixed pt
// block: 256 atoms, loops over kBG poses. grid: (391, B/kBG). NO atomics.
// ---------------------------------------------------------------------------
__global__ __launch_bounds__(256) void k_deform(
    const float* __restrict__ c_nma, const float* __restrict__ delta_euler,
    const float* __restrict__ delta_shifts, const float* __restrict__ coords,
    const float* __restrict__ basis_x, const float* __restrict__ basis_y,
    const float* __restrict__ basis_z, const float* __restrict__ euler_base,
    const float* __restrict__ shifts_base,
    unsigned* __restrict__ xy, float* __restrict__ bond, float* __restrict__ angle) {
  __shared__ float cn_s[kBG][kL];
  __shared__ float rsh_s[kBG][8];
  __shared__ float pt[258][3];

  const int t = threadIdx.x;
  const int n0 = blockIdx.x * 256;
  const int bg = blockIdx.y * kBG;

  if (t < kBG * kL) cn_s[t / kL][t % kL] = c_nma[(bg + t / kL) * kL + (t % kL)];
  if (t < kBG) {
    int b = bg + t;
    float rot  = euler_base[b * 3 + 0] + delta_euler[b * 3 + 0];
    float tilt = euler_base[b * 3 + 1] + delta_euler[b * 3 + 1];
    float psi  = euler_base[b * 3 + 2] + delta_euler[b * 3 + 2];
    float ca = cosf(rot), sa = sinf(rot);
    float cb = cosf(tilt), sb = sinf(tilt);
    float cg = cosf(psi), sg = sinf(psi);
    rsh_s[t][0] = cg * cb * ca - sg * sa;
    rsh_s[t][1] = cg * cb * sa + sg * ca;
    rsh_s[t][2] = -cg * sb;
    rsh_s[t][3] = -sg * cb * ca - cg * sa;
    rsh_s[t][4] = -sg * cb * sa + cg * ca;
    rsh_s[t][5] = sg * sb;
    rsh_s[t][6] = shifts_base[b * 2 + 0] + delta_shifts[b * 2 + 0] + 128.0f;
    rsh_s[t][7] = shifts_base[b * 2 + 1] + delta_shifts[b * 2 + 1] + 128.0f;
  }

  const int n = n0 + t;
  const bool valid = n < kN;
  float cx = 0.f, cy = 0.f, cz = 0.f;
  float bx[kL], by[kL], bz[kL];
#pragma unroll
  for (int l = 0; l < kL; ++l) { bx[l] = 0.f; by[l] = 0.f; bz[l] = 0.f; }
  if (valid) {
    cx = coords[n * 3 + 0]; cy = coords[n * 3 + 1]; cz = coords[n * 3 + 2];
    const float4* px4 = reinterpret_cast<const float4*>(basis_x + (size_t)n * kL);
    const float4* py4 = reinterpret_cast<const float4*>(basis_y + (size_t)n * kL);
    const float4* pz4 = reinterpret_cast<const float4*>(basis_z + (size_t)n * kL);
#pragma unroll
    for (int q = 0; q < 3; ++q) {
      float4 vx = px4[q], vy = py4[q], vz = pz4[q];
      bx[q * 4 + 0] = vx.x; bx[q * 4 + 1] = vx.y; bx[q * 4 + 2] = vx.z; bx[q * 4 + 3] = vx.w;
      by[q * 4 + 0] = vy.x; by[q * 4 + 1] = vy.y; by[q * 4 + 2] = vy.z; by[q * 4 + 3] = vy.w;
      bz[q * 4 + 0] = vz.x; bz[q * 4 + 1] = vz.y; bz[q * 4 + 2] = vz.z; bz[q * 4 + 3] = vz.w;
    }
  }
  __syncthreads();

  for (int bi = 0; bi < kBG; ++bi) {
    const int b = bg + bi;
    float px = cx, py = cy, pz = cz;
#pragma unroll
    for (int l = 0; l < kL; ++l) {
      float cc = cn_s[bi][l];
      px = fmaf(cc, bx[l], px);
      py = fmaf(cc, by[l], py);
      pz = fmaf(cc, bz[l], pz);
    }
    if (valid) { pt[t][0] = px; pt[t][1] = py; pt[t][2] = pz; }
    if (t < 2) {  // halo: atoms n0+256, n0+257 for bond/angle neighbors
      int nh = n0 + 256 + t;
      if (nh < kN) {
        float hx = coords[nh * 3 + 0], hy = coords[nh * 3 + 1], hz = coords[nh * 3 + 2];
        const float* hbx = basis_x + (size_t)nh * kL;
        const float* hby = basis_y + (size_t)nh * kL;
        const float* hbz = basis_z + (size_t)nh * kL;
#pragma unroll
        for (int l = 0; l < kL; ++l) {
          float cc = cn_s[bi][l];
          hx = fmaf(cc, hbx[l], hx);
          hy = fmaf(cc, hby[l], hy);
          hz = fmaf(cc, hbz[l], hz);
        }
        pt[256 + t][0] = hx; pt[256 + t][1] = hy; pt[256 + t][2] = hz;
      }
    }
    __syncthreads();
    if (valid) {
      // projection; quantize to u16.8 fixed point (floor), pack (y<<16)|x
      float xr = fmaf(rsh_s[bi][0], px, fmaf(rsh_s[bi][1], py, fmaf(rsh_s[bi][2], pz, rsh_s[bi][6])));
      float yr = fmaf(rsh_s[bi][3], px, fmaf(rsh_s[bi][4], py, fmaf(rsh_s[bi][5], pz, rsh_s[bi][7])));
      xr = fminf(fmaxf(xr, 0.0f), 254.999f);
      yr = fminf(fmaxf(yr, 0.0f), 254.999f);
      unsigned xf = (unsigned)(xr * 256.0f);   // <= 65279 -> x0 <= 254
      unsigned yf = (unsigned)(yr * 256.0f);
      xy[(size_t)b * kN + n] = (yf << 16) | xf;
      // bond length
      if (n < kN - 1) {
        float dx = pt[t + 1][0] - px, dy = pt[t + 1][1] - py, dz = pt[t + 1][2] - pz;
        bond[(size_t)b * (kN - 1) + n] =
            sqrtf(fmaf(dx, dx, fmaf(dy, dy, fmaf(dz, dz, 1e-12f))));
      }
      // angle at interior atom n+1
      if (n < kN - 2) {
        float mx = pt[t + 1][0], my = pt[t + 1][1], mz = pt[t + 1][2];
        float ux = px - mx, uy = py - my, uz = pz - mz;
        float vx = pt[t + 2][0] - mx, vy = pt[t + 2][1] - my, vz = pt[t + 2][2] - mz;
        float uu = ux * ux + uy * uy + uz * uz;
        float vv = vx * vx + vy * vy + vz * vz;
        float uv = ux * vx + uy * vy + uz * vz;
        float cosang = uv / (sqrtf(uu) * sqrtf(vv) + 1e-12f);
        cosang = fminf(fmaxf(cosang, -0.9999f), 0.9999f);
        angle[(size_t)b * (kN - 2) + n] = acosf(cosang);
      }
    }
    __syncthreads();
  }
}

// ---------------------------------------------------------------------------
// Phase B: bilinear splat via LDS tile accumulation.
// One block of 1024 threads (16 waves) per (pose, 32-row band): scans the
// pose's full xy list, LDS-atomic accumulates atoms in band into a 33x256
// tile, writes out with plain stores (boundary rows 0 and 32 via global
// atomics -- shared with adjacent bands). grid: 32 poses * 8 bands = 256.
// ---------------------------------------------------------------------------
__global__ __launch_bounds__(1024) void k_splat(const unsigned* __restrict__ xy,
                                                float* __restrict__ img) {
  __shared__ float tile[33 * 256];
  const int t = threadIdx.x;
  const int b = blockIdx.x >> 3;
  const int band = blockIdx.x & 7;
  const int r0 = band * 32;
  for (int i = t; i < 33 * 256; i += 1024) tile[i] = 0.f;
  __syncthreads();

  const uint4* xy4 = reinterpret_cast<const uint4*>(xy + (size_t)b * kN);
  for (int i = t; i < kN / 4; i += 1024) {
    uint4 u4 = xy4[i];
    unsigned us[4] = {u4.x, u4.y, u4.z, u4.w};
#pragma unroll
    for (int j = 0; j < 4; ++j) {
      unsigned u = us[j];
      int yf = (int)(u >> 16);
      int ry = (yf >> 8) - r0;
      if ((unsigned)ry < 32u) {
        int xf = (int)(u & 0xFFFFu);
        int x0 = xf >> 8;
        float fx = (float)(xf & 255) * (1.0f / 256.0f);
        float fy = (float)(yf & 255) * (1.0f / 256.0f);
        float* tb = tile + ry * 256 + x0;
        atomicAdd(tb,       (1.f - fx) * (1.f - fy));
        atomicAdd(tb + 1,   fx * (1.f - fy));
        atomicAdd(tb + 256, (1.f - fx) * fy);
        atomicAdd(tb + 257, fx * fy);
      }
    }
  }
  __syncthreads();

  const int col = t & 255;
  for (int r = (t >> 8); r < 33; r += 4) {
    int row = r0 + r;
    if (row >= kS) continue;                    // band 7 has no row 256
    float v = tile[r * 256 + col];
    float* p = img + ((size_t)b * kS + row) * kS + col;
    if (r == 0 || r == 32) unsafeAtomicAdd(p, v);
    else                   *p = v;
  }
}

// ---------------------------------------------------------------------------
// FFT passes. Spectrum lives TRANSPOSED: FcT[b][kx][ky] so the column pass is
// fully coalesced; row passes transpose via LDS in 32B chunks.
// ---------------------------------------------------------------------------
__global__ __launch_bounds__(256) void k_fft_rows_fwd(const float* __restrict__ img,
                                                      float2* __restrict__ FcT) {
  __shared__ float2 smres[4][256];
  __shared__ float2 smtmp[2][256];
  __shared__ float2 tw[128];
  const int t = threadIdx.x, half = t >> 7, lane = t & 127;
  build_tw(tw, t);
  const int b = blockIdx.x >> 6;
  const int y0 = (blockIdx.x & 63) * 4;
  __syncthreads();
#pragma unroll
  for (int q = 0; q < 2; ++q) {
    int j = q * 2 + half;
    const float* row = img + ((size_t)b * kS + y0 + j) * kS;
    float2* a = smres[j];
    a[lane]       = make_float2(row[lane], 0.f);
    a[lane + 128] = make_float2(row[lane + 128], 0.f);
    fft256t<-1>(a, smtmp[half], lane, tw);
  }
  // transpose write: thread t = kx, 4 consecutive ky -> 32B contiguous
  float2 v0 = smres[0][t], v1 = smres[1][t], v2 = smres[2][t], v3 = smres[3][t];
  float4* o = reinterpret_cast<float4*>(FcT + ((size_t)b * kS + t) * kS + y0);
  o[0] = make_float4(v0.x, v0.y, v1.x, v1.y);
  o[1] = make_float4(v2.x, v2.y, v3.x, v3.y);
}

__global__ __launch_bounds__(256) void k_fft_cols(float2* __restrict__ FcT,
                                                  const float* __restrict__ defocus) {
  __shared__ float2 sm[4][256];
  __shared__ float2 tw[128];
  const int t = threadIdx.x, half = t >> 7, lane = t & 127;
  build_tw(tw, t);
  const int c = blockIdx.x * 2 + half;  // global column id in [0, B*256)
  const int b = c >> 8, kx = c & 255;
  float2* col = FcT + (size_t)c * kS;   // contiguous column
  float2* a = sm[half * 2];
  float2* bb = sm[half * 2 + 1];
  __syncthreads();
  a[lane]       = col[lane];
  a[lane + 128] = col[lane + 128];
  float2* r1 = fft256t<-1>(a, bb, lane, tw);

  // apply real filter H(ky,kx) = G * CTF (defocus-dependent per pose)
  const float D = defocus[b];
  const float fxv = (float)(kx < 128 ? kx : kx - 256) * (1.0f / 256.0f);
  const float fx2 = fxv * fxv;
#pragma unroll
  for (int h = 0; h < 2; ++h) {
    int ky = lane + h * 128;
    float fyv = (float)(ky < 128 ? ky : ky - 256) * (1.0f / 256.0f);
    float s2 = fyv * fyv + fx2;
    float G = __expf(-kGauss * s2);
    float chi = kA1 * D * s2 - kA2 * s2 * s2;
    float sn, cn;
    sincosf(chi, &sn, &cn);
    float H = G * (-(kW1 * sn + kQ0 * cn));
    r1[ky].x *= H;
    r1[ky].y *= H;
  }
  float2* r2 = (r1 == a) ? bb : a;
  float2* res = fft256t<1>(r1, r2, lane, tw);
  col[lane]       = res[lane];
  col[lane + 128] = res[lane + 128];
}

__global__ __launch_bounds__(256) void k_fft_rows_inv(const float2* __restrict__ FcT,
                                                      float* __restrict__ out) {
  __shared__ float2 smres[4][256];
  __shared__ float2 smtmp[2][256];
  __shared__ float2 tw[128];
  const int t = threadIdx.x, half = t >> 7, lane = t & 127;
  build_tw(tw, t);
  const int b = blockIdx.x >> 6;
  const int ky0 = (blockIdx.x & 63) * 4;
  // transpose read: thread t = kx, 4 consecutive ky = 32B contiguous
  const float4* ip = reinterpret_cast<const float4*>(FcT + ((size_t)b * kS + t) * kS + ky0);
  float4 w0 = ip[0], w1 = ip[1];
  smres[0][t] = make_float2(w0.x, w0.y);
  smres[1][t] = make_float2(w0.z, w0.w);
  smres[2][t] = make_float2(w1.x, w1.y);
  smres[3][t] = make_float2(w1.z, w1.w);
  __syncthreads();
#pragma unroll
  for (int q = 0; q < 2; ++q) {
    int j = q * 2 + half;
    float2* res = fft256t<1>(smres[j], smtmp[half], lane, tw);
    float* orow = out + ((size_t)b * kS + ky0 + j) * kS;
    orow[lane]       = res[lane].x * (1.0f / 65536.0f);
    orow[lane + 128] = res[lane + 128].x * (1.0f / 65536.0f);
  }
}

// ---------------------------------------------------------------------------
extern "C" void kernel_launch(void* const* d_in, const int* in_sizes, int n_in,
                              void* d_out, int out_size, void* d_ws, size_t ws_size,
                              hipStream_t stream) {
  const float* c_nma        = (const float*)d_in[0];
  const float* delta_euler  = (const float*)d_in[1];
  const float* delta_shifts = (const float*)d_in[2];
  const float* coords       = (const float*)d_in[3];
  const float* basis_x      = (const float*)d_in[4];
  const float* basis_y      = (const float*)d_in[5];
  const float* basis_z      = (const float*)d_in[6];
  const float* euler_base   = (const float*)d_in[7];
  const float* shifts_base  = (const float*)d_in[8];
  const float* defocus      = (const float*)d_in[9];

  float* out = (float*)d_out;
  float* decoded = out;                                   // B*S*S
  float* bond    = out + (size_t)kB * kS * kS;            // B*(N-1)
  float* angle   = bond + (size_t)kB * (kN - 1);          // B*(N-2)

  char* ws = (char*)d_ws;
  const size_t imgBytes = (size_t)kB * kS * kS * sizeof(float);  // 8 MB
  float*    img = (float*)ws;                      // [0, 8MB)
  unsigned* xy  = (unsigned*)(ws + imgBytes);      // [8MB, 20.8MB)  dead after k_splat
  float2*   FcT = (float2*)(ws + imgBytes);        // [8MB, 24.8MB)  aliases xy

  hipMemsetAsync(img, 0, imgBytes, stream);

  dim3 gd(kNB, kB / kBG);
  k_deform<<<gd, 256, 0, stream>>>(c_nma, delta_euler, delta_shifts, coords,
                                   basis_x, basis_y, basis_z, euler_base,
                                   shifts_base, xy, bond, angle);
  k_splat<<<kB * 8, 1024, 0, stream>>>(xy, img);
  k_fft_rows_fwd<<<kB * 64, 256, 0, stream>>>(img, FcT);
  k_fft_cols<<<kB * kS / 2, 256, 0, stream>>>(FcT, defocus);
  k_fft_rows_inv<<<kB * 64, 256, 0, stream>>>(FcT, decoded);
}

// Round 4
// 207.682 us; speedup vs baseline: 3.4022x; 1.1905x over previous
//
#include <hip/hip_runtime.h>
#include <math.h>

namespace {
constexpr int kB = 32;
constexpr int kN = 100000;
constexpr int kL = 12;
constexpr int kS = 256;
constexpr int kBG = 8;                      // poses per block in deform kernel
constexpr int kNB = (kN + 255) / 256;       // 391 atom-blocks
constexpr int kCap = 16384;                 // per-(pose,band) bucket capacity

constexpr float kGauss = (float)(2.0 * M_PI * M_PI);                         // 2(pi*sigma)^2, sigma=1
constexpr float kA1 = (float)(M_PI * 0.0197);                                // pi*lambda
constexpr float kA2 = (float)(0.5 * M_PI * 2.7e7 * 0.0197 * 0.0197 * 0.0197);// 0.5*pi*Cs*lambda^3
constexpr float kW1 = 0.99498743710661995f;                                  // sqrt(1-Q0^2)
constexpr float kQ0 = 0.1f;
}

// ---------------------------------------------------------------------------
// 256-point Stockham radix-2 FFT in LDS with a shared twiddle table.
// 128 lanes per FFT, 8 stages, auto-sorting. Result ends in buffer `a`.
// tw[k] = (cos, sin)(pi*k/128); SIGN=-1 forward, +1 inverse.
// Contains __syncthreads(): all 256 threads of the block must call uniformly.
// ---------------------------------------------------------------------------
template <int SIGN>
__device__ __forceinline__ float2* fft256t(float2* a, float2* b, int lane,
                                           const float2* tw) {
#pragma unroll
  for (int m = 1; m <= 128; m <<= 1) {
    float2 c0 = a[lane];
    float2 c1 = a[lane + 128];
    int jm = lane & ~(m - 1);
    float2 w = tw[jm];
    float c = w.x;
    float s = (SIGN < 0) ? -w.y : w.y;
    float ex = c0.x + c1.x, ey = c0.y + c1.y;
    float dx = c0.x - c1.x, dy = c0.y - c1.y;
    b[lane + jm]     = make_float2(ex, ey);
    b[lane + jm + m] = make_float2(c * dx - s * dy, c * dy + s * dx);
    __syncthreads();
    float2* tp = a; a = b; b = tp;
  }
  return a;  // 8 swaps -> result back in original `a` buffer
}

__device__ __forceinline__ void build_tw(float2* tw, int t) {
  if (t < 128) {
    float s, c;
    sincosf((float)M_PI / 128.0f * (float)t, &s, &c);
    tw[t] = make_float2(c, s);
  }
}

// ---------------------------------------------------------------------------
// Phase A: deformation -> bond, angle, projected (x,y) packed u16.8, written
// into per-(pose, 32-row band) compact bucket lists (LDS rank + one global
// atomicAdd per (block, band) to reserve a contiguous segment).
// block: 256 atoms, loops over kBG poses. grid: (391, B/kBG).
// ---------------------------------------------------------------------------
__global__ __launch_bounds__(256) void k_deform(
    const float* __restrict__ c_nma, const float* __restrict__ delta_euler,
    const float* __restrict__ delta_shifts, const float* __restrict__ coords,
    const float* __restrict__ basis_x, const float* __restrict__ basis_y,
    const float* __restrict__ basis_z, const float* __restrict__ euler_base,
    const float* __restrict__ shifts_base,
    unsigned* __restrict__ xy_bkt, int* __restrict__ gcount,
    float* __restrict__ bond, float* __restrict__ angle) {
  __shared__ float cn_s[kBG][kL];
  __shared__ float rsh_s[kBG][8];
  __shared__ float pt[258][3];
  __shared__ int bcnt[8];
  __shared__ int bbase[8];

  const int t = threadIdx.x;
  const int n0 = blockIdx.x * 256;
  const int bg = blockIdx.y * kBG;

  if (t < kBG * kL) cn_s[t / kL][t % kL] = c_nma[(bg + t / kL) * kL + (t % kL)];
  if (t < kBG) {
    int b = bg + t;
    float rot  = euler_base[b * 3 + 0] + delta_euler[b * 3 + 0];
    float tilt = euler_base[b * 3 + 1] + delta_euler[b * 3 + 1];
    float psi  = euler_base[b * 3 + 2] + delta_euler[b * 3 + 2];
    float ca = cosf(rot), sa = sinf(rot);
    float cb = cosf(tilt), sb = sinf(tilt);
    float cg = cosf(psi), sg = sinf(psi);
    rsh_s[t][0] = cg * cb * ca - sg * sa;
    rsh_s[t][1] = cg * cb * sa + sg * ca;
    rsh_s[t][2] = -cg * sb;
    rsh_s[t][3] = -sg * cb * ca - cg * sa;
    rsh_s[t][4] = -sg * cb * sa + cg * ca;
    rsh_s[t][5] = sg * sb;
    rsh_s[t][6] = shifts_base[b * 2 + 0] + delta_shifts[b * 2 + 0] + 128.0f;
    rsh_s[t][7] = shifts_base[b * 2 + 1] + delta_shifts[b * 2 + 1] + 128.0f;
  }

  const int n = n0 + t;
  const bool valid = n < kN;
  float cx = 0.f, cy = 0.f, cz = 0.f;
  float bx[kL], by[kL], bz[kL];
#pragma unroll
  for (int l = 0; l < kL; ++l) { bx[l] = 0.f; by[l] = 0.f; bz[l] = 0.f; }
  if (valid) {
    cx = coords[n * 3 + 0]; cy = coords[n * 3 + 1]; cz = coords[n * 3 + 2];
    const float4* px4 = reinterpret_cast<const float4*>(basis_x + (size_t)n * kL);
    const float4* py4 = reinterpret_cast<const float4*>(basis_y + (size_t)n * kL);
    const float4* pz4 = reinterpret_cast<const float4*>(basis_z + (size_t)n * kL);
#pragma unroll
    for (int q = 0; q < 3; ++q) {
      float4 vx = px4[q], vy = py4[q], vz = pz4[q];
      bx[q * 4 + 0] = vx.x; bx[q * 4 + 1] = vx.y; bx[q * 4 + 2] = vx.z; bx[q * 4 + 3] = vx.w;
      by[q * 4 + 0] = vy.x; by[q * 4 + 1] = vy.y; by[q * 4 + 2] = vy.z; by[q * 4 + 3] = vy.w;
      bz[q * 4 + 0] = vz.x; bz[q * 4 + 1] = vz.y; bz[q * 4 + 2] = vz.z; bz[q * 4 + 3] = vz.w;
    }
  }
  __syncthreads();

  for (int bi = 0; bi < kBG; ++bi) {
    const int b = bg + bi;
    float px = cx, py = cy, pz = cz;
#pragma unroll
    for (int l = 0; l < kL; ++l) {
      float cc = cn_s[bi][l];
      px = fmaf(cc, bx[l], px);
      py = fmaf(cc, by[l], py);
      pz = fmaf(cc, bz[l], pz);
    }
    if (valid) { pt[t][0] = px; pt[t][1] = py; pt[t][2] = pz; }
    if (t < 2) {  // halo: atoms n0+256, n0+257 for bond/angle neighbors
      int nh = n0 + 256 + t;
      if (nh < kN) {
        float hx = coords[nh * 3 + 0], hy = coords[nh * 3 + 1], hz = coords[nh * 3 + 2];
        const float* hbx = basis_x + (size_t)nh * kL;
        const float* hby = basis_y + (size_t)nh * kL;
        const float* hbz = basis_z + (size_t)nh * kL;
#pragma unroll
        for (int l = 0; l < kL; ++l) {
          float cc = cn_s[bi][l];
          hx = fmaf(cc, hbx[l], hx);
          hy = fmaf(cc, hby[l], hy);
          hz = fmaf(cc, hbz[l], hz);
        }
        pt[256 + t][0] = hx; pt[256 + t][1] = hy; pt[256 + t][2] = hz;
      }
    }
    if (t < 8) bcnt[t] = 0;
    __syncthreads();

    unsigned u = 0, band = 0;
    int rank = 0;
    if (valid) {
      // projection; quantize to u16.8 fixed point (floor), pack (y<<16)|x
      float xr = fmaf(rsh_s[bi][0], px, fmaf(rsh_s[bi][1], py, fmaf(rsh_s[bi][2], pz, rsh_s[bi][6])));
      float yr = fmaf(rsh_s[bi][3], px, fmaf(rsh_s[bi][4], py, fmaf(rsh_s[bi][5], pz, rsh_s[bi][7])));
      xr = fminf(fmaxf(xr, 0.0f), 254.999f);
      yr = fminf(fmaxf(yr, 0.0f), 254.999f);
      unsigned xf = (unsigned)(xr * 256.0f);   // <= 65279 -> x0 <= 254
      unsigned yf = (unsigned)(yr * 256.0f);
      u = (yf << 16) | xf;
      band = yf >> 13;                         // row>>5, 0..7
      rank = atomicAdd(&bcnt[band], 1);
      // bond length
      if (n < kN - 1) {
        float dx = pt[t + 1][0] - px, dy = pt[t + 1][1] - py, dz = pt[t + 1][2] - pz;
        bond[(size_t)b * (kN - 1) + n] =
            sqrtf(fmaf(dx, dx, fmaf(dy, dy, fmaf(dz, dz, 1e-12f))));
      }
      // angle at interior atom n+1
      if (n < kN - 2) {
        float mx = pt[t + 1][0], my = pt[t + 1][1], mz = pt[t + 1][2];
        float ux = px - mx, uy = py - my, uz = pz - mz;
        float vx = pt[t + 2][0] - mx, vy = pt[t + 2][1] - my, vz = pt[t + 2][2] - mz;
        float uu = ux * ux + uy * uy + uz * uz;
        float vv = vx * vx + vy * vy + vz * vz;
        float uv = ux * vx + uy * vy + uz * vz;
        float cosang = uv / (sqrtf(uu) * sqrtf(vv) + 1e-12f);
        cosang = fminf(fmaxf(cosang, -0.9999f), 0.9999f);
        angle[(size_t)b * (kN - 2) + n] = acosf(cosang);
      }
    }
    __syncthreads();
    if (t < 8) {
      int c = bcnt[t];
      bbase[t] = c ? atomicAdd(&gcount[b * 8 + t], c) : 0;
    }
    __syncthreads();
    if (valid) {
      int pos = bbase[band] + rank;
      if (pos < kCap) xy_bkt[((size_t)b * 8 + band) * kCap + pos] = u;
    }
    __syncthreads();
  }
}

// ---------------------------------------------------------------------------
// Phase B: bilinear splat from per-(pose,band) compact lists into a 33x256
// LDS tile; plain stores out (boundary rows 0/32 via global atomics).
// grid: 32 poses * 8 bands = 256 blocks, 1024 threads.
// ---------------------------------------------------------------------------
__global__ __launch_bounds__(1024) void k_splat(const unsigned* __restrict__ xy_bkt,
                                                const int* __restrict__ gcount,
                                                float* __restrict__ img) {
  __shared__ float tile[33 * 256];
  const int t = threadIdx.x;
  const int b = blockIdx.x >> 3;
  const int band = blockIdx.x & 7;
  const int r0 = band * 32;
  for (int i = t; i < 33 * 256; i += 1024) tile[i] = 0.f;
  __syncthreads();

  const int c = min(gcount[b * 8 + band], kCap);
  const unsigned* seg = xy_bkt + ((size_t)b * 8 + band) * kCap;
  for (int i = t; i < c; i += 1024) {
    unsigned u = seg[i];
    int yf = (int)(u >> 16);
    int xf = (int)(u & 0xFFFFu);
    int ry = (yf >> 8) - r0;                 // guaranteed 0..31 by bucketing
    int x0 = xf >> 8;
    float fx = (float)(xf & 255) * (1.0f / 256.0f);
    float fy = (float)(yf & 255) * (1.0f / 256.0f);
    int base = ry * 256 + x0;
    atomicAdd(&tile[base],       (1.f - fx) * (1.f - fy));
    atomicAdd(&tile[base + 1],   fx * (1.f - fy));
    atomicAdd(&tile[base + 256], (1.f - fx) * fy);
    atomicAdd(&tile[base + 257], fx * fy);
  }
  __syncthreads();

  const int col = t & 255;
  for (int r = (t >> 8); r < 33; r += 4) {
    int row = r0 + r;
    if (row >= kS) continue;                 // band 7 has no row 256
    float v = tile[r * 256 + col];
    float* p = img + ((size_t)b * kS + row) * kS + col;
    if (r == 0 || r == 32) unsafeAtomicAdd(p, v);
    else                   *p = v;
  }
}

// ---------------------------------------------------------------------------
// FFT passes. Spectrum lives TRANSPOSED: FcT[b][kx][ky] so the column pass is
// fully coalesced; row passes transpose via LDS in 32B chunks.
// ---------------------------------------------------------------------------
__global__ __launch_bounds__(256) void k_fft_rows_fwd(const float* __restrict__ img,
                                                      float2* __restrict__ FcT) {
  __shared__ float2 smres[4][256];
  __shared__ float2 smtmp[2][256];
  __shared__ float2 tw[128];
  const int t = threadIdx.x, half = t >> 7, lane = t & 127;
  build_tw(tw, t);
  const int b = blockIdx.x >> 6;
  const int y0 = (blockIdx.x & 63) * 4;
  __syncthreads();
#pragma unroll
  for (int q = 0; q < 2; ++q) {
    int j = q * 2 + half;
    const float* row = img + ((size_t)b * kS + y0 + j) * kS;
    float2* a = smres[j];
    a[lane]       = make_float2(row[lane], 0.f);
    a[lane + 128] = make_float2(row[lane + 128], 0.f);
    fft256t<-1>(a, smtmp[half], lane, tw);
  }
  // transpose write: thread t = kx, 4 consecutive ky -> 32B contiguous
  float2 v0 = smres[0][t], v1 = smres[1][t], v2 = smres[2][t], v3 = smres[3][t];
  float4* o = reinterpret_cast<float4*>(FcT + ((size_t)b * kS + t) * kS + y0);
  o[0] = make_float4(v0.x, v0.y, v1.x, v1.y);
  o[1] = make_float4(v2.x, v2.y, v3.x, v3.y);
}

__global__ __launch_bounds__(256) void k_fft_cols(float2* __restrict__ FcT,
                                                  const float* __restrict__ defocus) {
  __shared__ float2 sm[4][256];
  __shared__ float2 tw[128];
  const int t = threadIdx.x, half = t >> 7, lane = t & 127;
  build_tw(tw, t);
  const int c = blockIdx.x * 2 + half;  // global column id in [0, B*256)
  const int b = c >> 8, kx = c & 255;
  float2* col = FcT + (size_t)c * kS;   // contiguous column
  float2* a = sm[half * 2];
  float2* bb = sm[half * 2 + 1];
  __syncthreads();
  a[lane]       = col[lane];
  a[lane + 128] = col[lane + 128];
  float2* r1 = fft256t<-1>(a, bb, lane, tw);

  // apply real filter H(ky,kx) = G * CTF (defocus-dependent per pose)
  const float D = defocus[b];
  const float fxv = (float)(kx < 128 ? kx : kx - 256) * (1.0f / 256.0f);
  const float fx2 = fxv * fxv;
#pragma unroll
  for (int h = 0; h < 2; ++h) {
    int ky = lane + h * 128;
    float fyv = (float)(ky < 128 ? ky : ky - 256) * (1.0f / 256.0f);
    float s2 = fyv * fyv + fx2;
    float G = __expf(-kGauss * s2);
    float chi = kA1 * D * s2 - kA2 * s2 * s2;
    float sn, cn;
    sincosf(chi, &sn, &cn);
    float H = G * (-(kW1 * sn + kQ0 * cn));
    r1[ky].x *= H;
    r1[ky].y *= H;
  }
  float2* r2 = (r1 == a) ? bb : a;
  float2* res = fft256t<1>(r1, r2, lane, tw);
  col[lane]       = res[lane];
  col[lane + 128] = res[lane + 128];
}

__global__ __launch_bounds__(256) void k_fft_rows_inv(const float2* __restrict__ FcT,
                                                      float* __restrict__ out) {
  __shared__ float2 smres[4][256];
  __shared__ float2 smtmp[2][256];
  __shared__ float2 tw[128];
  const int t = threadIdx.x, half = t >> 7, lane = t & 127;
  build_tw(tw, t);
  const int b = blockIdx.x >> 6;
  const int ky0 = (blockIdx.x & 63) * 4;
  // transpose read: thread t = kx, 4 consecutive ky = 32B contiguous
  const float4* ip = reinterpret_cast<const float4*>(FcT + ((size_t)b * kS + t) * kS + ky0);
  float4 w0 = ip[0], w1 = ip[1];
  smres[0][t] = make_float2(w0.x, w0.y);
  smres[1][t] = make_float2(w0.z, w0.w);
  smres[2][t] = make_float2(w1.x, w1.y);
  smres[3][t] = make_float2(w1.z, w1.w);
  __syncthreads();
#pragma unroll
  for (int q = 0; q < 2; ++q) {
    int j = q * 2 + half;
    float2* res = fft256t<1>(smres[j], smtmp[half], lane, tw);
    float* orow = out + ((size_t)b * kS + ky0 + j) * kS;
    orow[lane]       = res[lane].x * (1.0f / 65536.0f);
    orow[lane + 128] = res[lane + 128].x * (1.0f / 65536.0f);
  }
}

// ---------------------------------------------------------------------------
extern "C" void kernel_launch(void* const* d_in, const int* in_sizes, int n_in,
                              void* d_out, int out_size, void* d_ws, size_t ws_size,
                              hipStream_t stream) {
  const float* c_nma        = (const float*)d_in[0];
  const float* delta_euler  = (const float*)d_in[1];
  const float* delta_shifts = (const float*)d_in[2];
  const float* coords       = (const float*)d_in[3];
  const float* basis_x      = (const float*)d_in[4];
  const float* basis_y      = (const float*)d_in[5];
  const float* basis_z      = (const float*)d_in[6];
  const float* euler_base   = (const float*)d_in[7];
  const float* shifts_base  = (const float*)d_in[8];
  const float* defocus      = (const float*)d_in[9];

  float* out = (float*)d_out;
  float* decoded = out;                                   // B*S*S
  float* bond    = out + (size_t)kB * kS * kS;            // B*(N-1)
  float* angle   = bond + (size_t)kB * (kN - 1);          // B*(N-2)

  char* ws = (char*)d_ws;
  const size_t imgBytes = (size_t)kB * kS * kS * sizeof(float);        // 8 MB
  const size_t bktBytes = (size_t)kB * 8 * kCap * sizeof(unsigned);    // 16 MB
  const size_t fctBytes = (size_t)kB * kS * kS * sizeof(float2);       // 16.8 MB
  float*    img    = (float*)ws;                           // [0, 8MB)
  unsigned* xy_bkt = (unsigned*)(ws + imgBytes);           // [8MB, 24MB)   dead after k_splat
  int*      gcount = (int*)(ws + imgBytes + fctBytes);     // [24.8MB, +1KB) dead after k_splat
  float2*   FcT    = (float2*)(ws + imgBytes);             // [8MB, 24.8MB) aliases xy_bkt (after splat)

  hipMemsetAsync(img, 0, imgBytes, stream);
  hipMemsetAsync(gcount, 0, (size_t)kB * 8 * sizeof(int), stream);

  dim3 gd(kNB, kB / kBG);
  k_deform<<<gd, 256, 0, stream>>>(c_nma, delta_euler, delta_shifts, coords,
                                   basis_x, basis_y, basis_z, euler_base,
                                   shifts_base, xy_bkt, gcount, bond, angle);
  k_splat<<<kB * 8, 1024, 0, stream>>>(xy_bkt, gcount, img);
  k_fft_rows_fwd<<<kB * 64, 256, 0, stream>>>(img, FcT);
  k_fft_cols<<<kB * kS / 2, 256, 0, stream>>>(FcT, defocus);
  k_fft_rows_inv<<<kB * 64, 256, 0, stream>>>(FcT, decoded);
}

// Round 5
// 128.747 us; speedup vs baseline: 5.4880x; 1.6131x over previous
//
#include <hip/hip_runtime.h>
#include <math.h>

namespace {
constexpr int kB = 32;
constexpr int kN = 100000;
constexpr int kL = 12;
constexpr int kS = 256;
constexpr int kBG = 8;                      // poses per block in deform kernel
constexpr int kNB = (kN + 255) / 256;       // 391 atom-blocks
constexpr int kCap = 16384;                 // per-(pose,band) bucket capacity

constexpr float kGauss = (float)(2.0 * M_PI * M_PI);                         // 2(pi*sigma)^2, sigma=1
constexpr float kA1 = (float)(M_PI * 0.0197);                                // pi*lambda
constexpr float kA2 = (float)(0.5 * M_PI * 2.7e7 * 0.0197 * 0.0197 * 0.0197);// 0.5*pi*Cs*lambda^3
constexpr float kW1 = 0.99498743710661995f;                                  // sqrt(1-Q0^2)
constexpr float kQ0 = 0.1f;
}

// ---------------------------------------------------------------------------
// 256-point Stockham radix-2 FFT in LDS with a shared twiddle table.
// 128 lanes per FFT, 8 stages, auto-sorting. Result ends in buffer `a`.
// tw[k] = (cos, sin)(pi*k/128); SIGN=-1 forward, +1 inverse.
// Contains __syncthreads(): all 256 threads of the block must call uniformly.
// ---------------------------------------------------------------------------
template <int SIGN>
__device__ __forceinline__ float2* fft256t(float2* a, float2* b, int lane,
                                           const float2* tw) {
#pragma unroll
  for (int m = 1; m <= 128; m <<= 1) {
    float2 c0 = a[lane];
    float2 c1 = a[lane + 128];
    int jm = lane & ~(m - 1);
    float2 w = tw[jm];
    float c = w.x;
    float s = (SIGN < 0) ? -w.y : w.y;
    float ex = c0.x + c1.x, ey = c0.y + c1.y;
    float dx = c0.x - c1.x, dy = c0.y - c1.y;
    b[lane + jm]     = make_float2(ex, ey);
    b[lane + jm + m] = make_float2(c * dx - s * dy, c * dy + s * dx);
    __syncthreads();
    float2* tp = a; a = b; b = tp;
  }
  return a;  // 8 swaps -> result back in original `a` buffer
}

__device__ __forceinline__ void build_tw(float2* tw, int t) {
  if (t < 128) {
    float s, c;
    sincosf((float)M_PI / 128.0f * (float)t, &s, &c);
    tw[t] = make_float2(c, s);
  }
}

// ---------------------------------------------------------------------------
// Phase A: deformation -> bond, angle, projected (x,y) packed u16.8, written
// into per-(pose, 32-row band) compact bucket lists (LDS rank + one global
// atomicAdd per (block, band) to reserve a contiguous segment).
// block: 256 atoms, loops over kBG poses. grid: (391, B/kBG).
// ---------------------------------------------------------------------------
__global__ __launch_bounds__(256) void k_deform(
    const float* __restrict__ c_nma, const float* __restrict__ delta_euler,
    const float* __restrict__ delta_shifts, const float* __restrict__ coords,
    const float* __restrict__ basis_x, const float* __restrict__ basis_y,
    const float* __restrict__ basis_z, const float* __restrict__ euler_base,
    const float* __restrict__ shifts_base,
    unsigned* __restrict__ xy_bkt, int* __restrict__ gcount,
    float* __restrict__ bond, float* __restrict__ angle) {
  __shared__ float cn_s[kBG][kL];
  __shared__ float rsh_s[kBG][8];
  __shared__ float pt[258][3];
  __shared__ int bcnt[8];
  __shared__ int bbase[8];

  const int t = threadIdx.x;
  const int n0 = blockIdx.x * 256;
  const int bg = blockIdx.y * kBG;

  if (t < kBG * kL) cn_s[t / kL][t % kL] = c_nma[(bg + t / kL) * kL + (t % kL)];
  if (t < kBG) {
    int b = bg + t;
    float rot  = euler_base[b * 3 + 0] + delta_euler[b * 3 + 0];
    float tilt = euler_base[b * 3 + 1] + delta_euler[b * 3 + 1];
    float psi  = euler_base[b * 3 + 2] + delta_euler[b * 3 + 2];
    float ca = cosf(rot), sa = sinf(rot);
    float cb = cosf(tilt), sb = sinf(tilt);
    float cg = cosf(psi), sg = sinf(psi);
    rsh_s[t][0] = cg * cb * ca - sg * sa;
    rsh_s[t][1] = cg * cb * sa + sg * ca;
    rsh_s[t][2] = -cg * sb;
    rsh_s[t][3] = -sg * cb * ca - cg * sa;
    rsh_s[t][4] = -sg * cb * sa + cg * ca;
    rsh_s[t][5] = sg * sb;
    rsh_s[t][6] = shifts_base[b * 2 + 0] + delta_shifts[b * 2 + 0] + 128.0f;
    rsh_s[t][7] = shifts_base[b * 2 + 1] + delta_shifts[b * 2 + 1] + 128.0f;
  }

  const int n = n0 + t;
  const bool valid = n < kN;
  float cx = 0.f, cy = 0.f, cz = 0.f;
  float bx[kL], by[kL], bz[kL];
#pragma unroll
  for (int l = 0; l < kL; ++l) { bx[l] = 0.f; by[l] = 0.f; bz[l] = 0.f; }
  if (valid) {
    cx = coords[n * 3 + 0]; cy = coords[n * 3 + 1]; cz = coords[n * 3 + 2];
    const float4* px4 = reinterpret_cast<const float4*>(basis_x + (size_t)n * kL);
    const float4* py4 = reinterpret_cast<const float4*>(basis_y + (size_t)n * kL);
    const float4* pz4 = reinterpret_cast<const float4*>(basis_z + (size_t)n * kL);
#pragma unroll
    for (int q = 0; q < 3; ++q) {
      float4 vx = px4[q], vy = py4[q], vz = pz4[q];
      bx[q * 4 + 0] = vx.x; bx[q * 4 + 1] = vx.y; bx[q * 4 + 2] = vx.z; bx[q * 4 + 3] = vx.w;
      by[q * 4 + 0] = vy.x; by[q * 4 + 1] = vy.y; by[q * 4 + 2] = vy.z; by[q * 4 + 3] = vy.w;
      bz[q * 4 + 0] = vz.x; bz[q * 4 + 1] = vz.y; bz[q * 4 + 2] = vz.z; bz[q * 4 + 3] = vz.w;
    }
  }
  __syncthreads();

  for (int bi = 0; bi < kBG; ++bi) {
    const int b = bg + bi;
    float px = cx, py = cy, pz = cz;
#pragma unroll
    for (int l = 0; l < kL; ++l) {
      float cc = cn_s[bi][l];
      px = fmaf(cc, bx[l], px);
      py = fmaf(cc, by[l], py);
      pz = fmaf(cc, bz[l], pz);
    }
    if (valid) { pt[t][0] = px; pt[t][1] = py; pt[t][2] = pz; }
    if (t < 2) {  // halo: atoms n0+256, n0+257 for bond/angle neighbors
      int nh = n0 + 256 + t;
      if (nh < kN) {
        float hx = coords[nh * 3 + 0], hy = coords[nh * 3 + 1], hz = coords[nh * 3 + 2];
        const float* hbx = basis_x + (size_t)nh * kL;
        const float* hby = basis_y + (size_t)nh * kL;
        const float* hbz = basis_z + (size_t)nh * kL;
#pragma unroll
        for (int l = 0; l < kL; ++l) {
          float cc = cn_s[bi][l];
          hx = fmaf(cc, hbx[l], hx);
          hy = fmaf(cc, hby[l], hy);
          hz = fmaf(cc, hbz[l], hz);
        }
        pt[256 + t][0] = hx; pt[256 + t][1] = hy; pt[256 + t][2] = hz;
      }
    }
    if (t < 8) bcnt[t] = 0;
    __syncthreads();

    unsigned u = 0, band = 0;
    int rank = 0;
    if (valid) {
      // projection; quantize to u16.8 fixed point (floor), pack (y<<16)|x
      float xr = fmaf(rsh_s[bi][0], px, fmaf(rsh_s[bi][1], py, fmaf(rsh_s[bi][2], pz, rsh_s[bi][6])));
      float yr = fmaf(rsh_s[bi][3], px, fmaf(rsh_s[bi][4], py, fmaf(rsh_s[bi][5], pz, rsh_s[bi][7])));
      xr = fminf(fmaxf(xr, 0.0f), 254.999f);
      yr = fminf(fmaxf(yr, 0.0f), 254.999f);
      unsigned xf = (unsigned)(xr * 256.0f);   // <= 65279 -> x0 <= 254
      unsigned yf = (unsigned)(yr * 256.0f);
      u = (yf << 16) | xf;
      band = yf >> 13;                         // row>>5, 0..7
      rank = atomicAdd(&bcnt[band], 1);
      // bond length
      if (n < kN - 1) {
        float dx = pt[t + 1][0] - px, dy = pt[t + 1][1] - py, dz = pt[t + 1][2] - pz;
        bond[(size_t)b * (kN - 1) + n] =
            sqrtf(fmaf(dx, dx, fmaf(dy, dy, fmaf(dz, dz, 1e-12f))));
      }
      // angle at interior atom n+1
      if (n < kN - 2) {
        float mx = pt[t + 1][0], my = pt[t + 1][1], mz = pt[t + 1][2];
        float ux = px - mx, uy = py - my, uz = pz - mz;
        float vx = pt[t + 2][0] - mx, vy = pt[t + 2][1] - my, vz = pt[t + 2][2] - mz;
        float uu = ux * ux + uy * uy + uz * uz;
        float vv = vx * vx + vy * vy + vz * vz;
        float uv = ux * vx + uy * vy + uz * vz;
        float cosang = uv / (sqrtf(uu) * sqrtf(vv) + 1e-12f);
        cosang = fminf(fmaxf(cosang, -0.9999f), 0.9999f);
        angle[(size_t)b * (kN - 2) + n] = acosf(cosang);
      }
    }
    __syncthreads();
    if (t < 8) {
      int c = bcnt[t];
      bbase[t] = c ? atomicAdd(&gcount[b * 8 + t], c) : 0;
    }
    __syncthreads();
    if (valid) {
      int pos = bbase[band] + rank;
      if (pos < kCap) xy_bkt[((size_t)b * 8 + band) * kCap + pos] = u;
    }
    __syncthreads();
  }
}

// ---------------------------------------------------------------------------
// Phase B: bilinear splat from per-(pose,band) compact lists into a 33x256
// INTEGER (u18.14 fixed-point) LDS tile via native ds_add_u32 atomics
// (float LDS atomicAdd compiles to a CAS loop without -munsafe-fp-atomics --
// measured ~270 cyc/atomic in round 4). Plain stores out (boundary rows 0/32
// via global float atomics). grid: 32 poses * 8 bands, 1024 threads.
// ---------------------------------------------------------------------------
__global__ __launch_bounds__(1024) void k_splat(const unsigned* __restrict__ xy_bkt,
                                                const int* __restrict__ gcount,
                                                float* __restrict__ img) {
  __shared__ unsigned tile[33 * 256];
  const int t = threadIdx.x;
  const int b = blockIdx.x >> 3;
  const int band = blockIdx.x & 7;
  const int r0 = band * 32;
  for (int i = t; i < 33 * 256; i += 1024) tile[i] = 0u;
  __syncthreads();

  const int c = min(gcount[b * 8 + band], kCap);
  const unsigned* seg = xy_bkt + ((size_t)b * 8 + band) * kCap;

  auto splat1 = [&](unsigned u) {
    int yf = (int)(u >> 16);
    int xf = (int)(u & 0xFFFFu);
    int ry = (yf >> 8) - r0;                 // guaranteed 0..31 by bucketing
    int x0 = xf >> 8;
    int fx = xf & 255, fy = yf & 255;        // u0.8 fractions
    int gx = 256 - fx, gy = 256 - fy;
    int base = ry * 256 + x0;
    // w * 2^14 = (w8a * w8b + 2) >> 2  (round-to-nearest-ish)
    atomicAdd(&tile[base],       (unsigned)((gx * gy + 2) >> 2));
    atomicAdd(&tile[base + 1],   (unsigned)((fx * gy + 2) >> 2));
    atomicAdd(&tile[base + 256], (unsigned)((gx * fy + 2) >> 2));
    atomicAdd(&tile[base + 257], (unsigned)((fx * fy + 2) >> 2));
  };

  // main loop: 4 atoms per thread per iteration (uint4, segment is 16B-aligned)
  const int c4 = c & ~3;
  const uint4* seg4 = reinterpret_cast<const uint4*>(seg);
  for (int i4 = t; i4 * 4 < c4; i4 += 1024) {
    uint4 q = seg4[i4];
    splat1(q.x); splat1(q.y); splat1(q.z); splat1(q.w);
  }
  for (int i = c4 + t; i < c; i += 1024) splat1(seg[i]);
  __syncthreads();

  const int col = t & 255;
  for (int r = (t >> 8); r < 33; r += 4) {
    int row = r0 + r;
    if (row >= kS) continue;                 // band 7 has no row 256
    float v = (float)tile[r * 256 + col] * (1.0f / 16384.0f);
    float* p = img + ((size_t)b * kS + row) * kS + col;
    if (r == 0 || r == 32) unsafeAtomicAdd(p, v);
    else                   *p = v;
  }
}

// ---------------------------------------------------------------------------
// FFT passes. Spectrum lives TRANSPOSED: FcT[b][kx][ky] so the column pass is
// fully coalesced; row passes transpose via LDS in 32B chunks.
// ---------------------------------------------------------------------------
__global__ __launch_bounds__(256) void k_fft_rows_fwd(const float* __restrict__ img,
                                                      float2* __restrict__ FcT) {
  __shared__ float2 smres[4][256];
  __shared__ float2 smtmp[2][256];
  __shared__ float2 tw[128];
  const int t = threadIdx.x, half = t >> 7, lane = t & 127;
  build_tw(tw, t);
  const int b = blockIdx.x >> 6;
  const int y0 = (blockIdx.x & 63) * 4;
  __syncthreads();
#pragma unroll
  for (int q = 0; q < 2; ++q) {
    int j = q * 2 + half;
    const float* row = img + ((size_t)b * kS + y0 + j) * kS;
    float2* a = smres[j];
    a[lane]       = make_float2(row[lane], 0.f);
    a[lane + 128] = make_float2(row[lane + 128], 0.f);
    fft256t<-1>(a, smtmp[half], lane, tw);
  }
  // transpose write: thread t = kx, 4 consecutive ky -> 32B contiguous
  float2 v0 = smres[0][t], v1 = smres[1][t], v2 = smres[2][t], v3 = smres[3][t];
  float4* o = reinterpret_cast<float4*>(FcT + ((size_t)b * kS + t) * kS + y0);
  o[0] = make_float4(v0.x, v0.y, v1.x, v1.y);
  o[1] = make_float4(v2.x, v2.y, v3.x, v3.y);
}

__global__ __launch_bounds__(256) void k_fft_cols(float2* __restrict__ FcT,
                                                  const float* __restrict__ defocus) {
  __shared__ float2 sm[4][256];
  __shared__ float2 tw[128];
  const int t = threadIdx.x, half = t >> 7, lane = t & 127;
  build_tw(tw, t);
  const int c = blockIdx.x * 2 + half;  // global column id in [0, B*256)
  const int b = c >> 8, kx = c & 255;
  float2* col = FcT + (size_t)c * kS;   // contiguous column
  float2* a = sm[half * 2];
  float2* bb = sm[half * 2 + 1];
  __syncthreads();
  a[lane]       = col[lane];
  a[lane + 128] = col[lane + 128];
  float2* r1 = fft256t<-1>(a, bb, lane, tw);

  // apply real filter H(ky,kx) = G * CTF (defocus-dependent per pose)
  const float D = defocus[b];
  const float fxv = (float)(kx < 128 ? kx : kx - 256) * (1.0f / 256.0f);
  const float fx2 = fxv * fxv;
#pragma unroll
  for (int h = 0; h < 2; ++h) {
    int ky = lane + h * 128;
    float fyv = (float)(ky < 128 ? ky : ky - 256) * (1.0f / 256.0f);
    float s2 = fyv * fyv + fx2;
    float G = __expf(-kGauss * s2);
    float chi = kA1 * D * s2 - kA2 * s2 * s2;
    float sn, cn;
    sincosf(chi, &sn, &cn);
    float H = G * (-(kW1 * sn + kQ0 * cn));
    r1[ky].x *= H;
    r1[ky].y *= H;
  }
  float2* r2 = (r1 == a) ? bb : a;
  float2* res = fft256t<1>(r1, r2, lane, tw);
  col[lane]       = res[lane];
  col[lane + 128] = res[lane + 128];
}

__global__ __launch_bounds__(256) void k_fft_rows_inv(const float2* __restrict__ FcT,
                                                      float* __restrict__ out) {
  __shared__ float2 smres[4][256];
  __shared__ float2 smtmp[2][256];
  __shared__ float2 tw[128];
  const int t = threadIdx.x, half = t >> 7, lane = t & 127;
  build_tw(tw, t);
  const int b = blockIdx.x >> 6;
  const int ky0 = (blockIdx.x & 63) * 4;
  // transpose read: thread t = kx, 4 consecutive ky = 32B contiguous
  const float4* ip = reinterpret_cast<const float4*>(FcT + ((size_t)b * kS + t) * kS + ky0);
  float4 w0 = ip[0], w1 = ip[1];
  smres[0][t] = make_float2(w0.x, w0.y);
  smres[1][t] = make_float2(w0.z, w0.w);
  smres[2][t] = make_float2(w1.x, w1.y);
  smres[3][t] = make_float2(w1.z, w1.w);
  __syncthreads();
#pragma unroll
  for (int q = 0; q < 2; ++q) {
    int j = q * 2 + half;
    float2* res = fft256t<1>(smres[j], smtmp[half], lane, tw);
    float* orow = out + ((size_t)b * kS + ky0 + j) * kS;
    orow[lane]       = res[lane].x * (1.0f / 65536.0f);
    orow[lane + 128] = res[lane + 128].x * (1.0f / 65536.0f);
  }
}

// ---------------------------------------------------------------------------
extern "C" void kernel_launch(void* const* d_in, const int* in_sizes, int n_in,
                              void* d_out, int out_size, void* d_ws, size_t ws_size,
                              hipStream_t stream) {
  const float* c_nma        = (const float*)d_in[0];
  const float* delta_euler  = (const float*)d_in[1];
  const float* delta_shifts = (const float*)d_in[2];
  const float* coords       = (const float*)d_in[3];
  const float* basis_x      = (const float*)d_in[4];
  const float* basis_y      = (const float*)d_in[5];
  const float* basis_z      = (const float*)d_in[6];
  const float* euler_base   = (const float*)d_in[7];
  const float* shifts_base  = (const float*)d_in[8];
  const float* defocus      = (const float*)d_in[9];

  float* out = (float*)d_out;
  float* decoded = out;                                   // B*S*S
  float* bond    = out + (size_t)kB * kS * kS;            // B*(N-1)
  float* angle   = bond + (size_t)kB * (kN - 1);          // B*(N-2)

  char* ws = (char*)d_ws;
  const size_t imgBytes = (size_t)kB * kS * kS * sizeof(float);        // 8 MB
  const size_t fctBytes = (size_t)kB * kS * kS * sizeof(float2);       // 16.8 MB
  float*    img    = (float*)ws;                           // [0, 8MB)
  unsigned* xy_bkt = (unsigned*)(ws + imgBytes);           // [8MB, 24MB)   dead after k_splat
  int*      gcount = (int*)(ws + imgBytes + fctBytes);     // [24.8MB, +1KB) dead after k_splat
  float2*   FcT    = (float2*)(ws + imgBytes);             // [8MB, 24.8MB) aliases xy_bkt (after splat)

  hipMemsetAsync(img, 0, imgBytes, stream);
  hipMemsetAsync(gcount, 0, (size_t)kB * 8 * sizeof(int), stream);

  dim3 gd(kNB, kB / kBG);
  k_deform<<<gd, 256, 0, stream>>>(c_nma, delta_euler, delta_shifts, coords,
                                   basis_x, basis_y, basis_z, euler_base,
                                   shifts_base, xy_bkt, gcount, bond, angle);
  k_splat<<<kB * 8, 1024, 0, stream>>>(xy_bkt, gcount, img);
  k_fft_rows_fwd<<<kB * 64, 256, 0, stream>>>(img, FcT);
  k_fft_cols<<<kB * kS / 2, 256, 0, stream>>>(FcT, defocus);
  k_fft_rows_inv<<<kB * 64, 256, 0, stream>>>(FcT, decoded);
}

// Round 6
// 100.323 us; speedup vs baseline: 7.0429x; 1.2833x over previous
//
#include <hip/hip_runtime.h>
#include <math.h>

namespace {
constexpr int kB = 32;
constexpr int kN = 100000;
constexpr int kL = 12;
constexpr int kS = 256;
constexpr int kBG = 8;                      // poses per block in deform kernel
constexpr int kTile = 254;                  // atoms OWNED per block (2 halo threads)
constexpr int kNB = (kN + kTile - 1) / kTile;  // 394 atom-blocks
constexpr int kCap = 16384;                 // per-(pose,band) bucket capacity

constexpr float kGauss = (float)(2.0 * M_PI * M_PI);                         // 2(pi*sigma)^2, sigma=1
constexpr float kA1 = (float)(M_PI * 0.0197);                                // pi*lambda
constexpr float kA2 = (float)(0.5 * M_PI * 2.7e7 * 0.0197 * 0.0197 * 0.0197);// 0.5*pi*Cs*lambda^3
constexpr float kW1 = 0.99498743710661995f;                                  // sqrt(1-Q0^2)
constexpr float kQ0 = 0.1f;
}

// ---------------------------------------------------------------------------
// 256-point Stockham radix-2 FFT in LDS with a shared twiddle table.
// 128 lanes per FFT, 8 stages, auto-sorting. Result ends in buffer `a`.
// tw[k] = (cos, sin)(pi*k/128); SIGN=-1 forward, +1 inverse.
// Contains __syncthreads(): all 256 threads of the block must call uniformly.
// ---------------------------------------------------------------------------
template <int SIGN>
__device__ __forceinline__ float2* fft256t(float2* a, float2* b, int lane,
                                           const float2* tw) {
#pragma unroll
  for (int m = 1; m <= 128; m <<= 1) {
    float2 c0 = a[lane];
    float2 c1 = a[lane + 128];
    int jm = lane & ~(m - 1);
    float2 w = tw[jm];
    float c = w.x;
    float s = (SIGN < 0) ? -w.y : w.y;
    float ex = c0.x + c1.x, ey = c0.y + c1.y;
    float dx = c0.x - c1.x, dy = c0.y - c1.y;
    b[lane + jm]     = make_float2(ex, ey);
    b[lane + jm + m] = make_float2(c * dx - s * dy, c * dy + s * dx);
    __syncthreads();
    float2* tp = a; a = b; b = tp;
  }
  return a;  // 8 swaps -> result back in original `a` buffer
}

__device__ __forceinline__ void build_tw(float2* tw, int t) {
  if (t < 128) {
    float s, c;
    sincosf((float)M_PI / 128.0f * (float)t, &s, &c);
    tw[t] = make_float2(c, s);
  }
}

// ---------------------------------------------------------------------------
// Phase A: deformation -> bond, angle, projected (x,y) packed u16.8 into
// per-(pose, 32-row band) compact bucket lists.
// Thread t owns atom blockIdx.x*254 + t; threads 254/255 are live halo
// (compute deform, write nothing). Double-buffered pt -> ONE barrier/pose.
// Per-pose (u, rank, band) buffered in registers; ONE global-atomic
// reservation round + one scatter phase at the end.
// ---------------------------------------------------------------------------
__global__ __launch_bounds__(256) void k_deform(
    const float* __restrict__ c_nma, const float* __restrict__ delta_euler,
    const float* __restrict__ delta_shifts, const float* __restrict__ coords,
    const float* __restrict__ basis_x, const float* __restrict__ basis_y,
    const float* __restrict__ basis_z, const float* __restrict__ euler_base,
    const float* __restrict__ shifts_base,
    unsigned* __restrict__ xy_bkt, int* __restrict__ gcount,
    float* __restrict__ bond, float* __restrict__ angle) {
  __shared__ float cn_s[kBG][kL];
  __shared__ float rsh_s[kBG][8];
  __shared__ float pt[2][256][3];
  __shared__ int bcnt[kBG][8];
  __shared__ int bbase[kBG][8];

  const int t = threadIdx.x;
  const int n0 = blockIdx.x * kTile;
  const int bg = blockIdx.y * kBG;
  const int n = n0 + t;
  const bool valid = n < kN;                    // thread has an atom (incl halo)
  const bool owner = (t < kTile) && valid;      // thread writes outputs

  if (t < kBG * kL) cn_s[t / kL][t % kL] = c_nma[(bg + t / kL) * kL + (t % kL)];
  if (t < kBG) {
    int b = bg + t;
    float rot  = euler_base[b * 3 + 0] + delta_euler[b * 3 + 0];
    float tilt = euler_base[b * 3 + 1] + delta_euler[b * 3 + 1];
    float psi  = euler_base[b * 3 + 2] + delta_euler[b * 3 + 2];
    float ca = cosf(rot), sa = sinf(rot);
    float cb = cosf(tilt), sb = sinf(tilt);
    float cg = cosf(psi), sg = sinf(psi);
    rsh_s[t][0] = cg * cb * ca - sg * sa;
    rsh_s[t][1] = cg * cb * sa + sg * ca;
    rsh_s[t][2] = -cg * sb;
    rsh_s[t][3] = -sg * cb * ca - cg * sa;
    rsh_s[t][4] = -sg * cb * sa + cg * ca;
    rsh_s[t][5] = sg * sb;
    rsh_s[t][6] = shifts_base[b * 2 + 0] + delta_shifts[b * 2 + 0] + 128.0f;
    rsh_s[t][7] = shifts_base[b * 2 + 1] + delta_shifts[b * 2 + 1] + 128.0f;
  }
  if (t < kBG * 8) bcnt[t >> 3][t & 7] = 0;

  float cx = 0.f, cy = 0.f, cz = 0.f;
  float bx[kL], by[kL], bz[kL];
#pragma unroll
  for (int l = 0; l < kL; ++l) { bx[l] = 0.f; by[l] = 0.f; bz[l] = 0.f; }
  if (valid) {
    cx = coords[n * 3 + 0]; cy = coords[n * 3 + 1]; cz = coords[n * 3 + 2];
    const float4* px4 = reinterpret_cast<const float4*>(basis_x + (size_t)n * kL);
    const float4* py4 = reinterpret_cast<const float4*>(basis_y + (size_t)n * kL);
    const float4* pz4 = reinterpret_cast<const float4*>(basis_z + (size_t)n * kL);
#pragma unroll
    for (int q = 0; q < 3; ++q) {
      float4 vx = px4[q], vy = py4[q], vz = pz4[q];
      bx[q * 4 + 0] = vx.x; bx[q * 4 + 1] = vx.y; bx[q * 4 + 2] = vx.z; bx[q * 4 + 3] = vx.w;
      by[q * 4 + 0] = vy.x; by[q * 4 + 1] = vy.y; by[q * 4 + 2] = vy.z; by[q * 4 + 3] = vy.w;
      bz[q * 4 + 0] = vz.x; bz[q * 4 + 1] = vz.y; bz[q * 4 + 2] = vz.z; bz[q * 4 + 3] = vz.w;
    }
  }
  __syncthreads();

  unsigned ureg[kBG];   // packed (y<<16)|x per pose
  unsigned meta[kBG];   // (rank<<3)|band per pose

#pragma unroll
  for (int bi = 0; bi < kBG; ++bi) {
    const int cur = bi & 1;
    const int b = bg + bi;
    float px = cx, py = cy, pz = cz;
#pragma unroll
    for (int l = 0; l < kL; ++l) {
      float cc = cn_s[bi][l];
      px = fmaf(cc, bx[l], px);
      py = fmaf(cc, by[l], py);
      pz = fmaf(cc, bz[l], pz);
    }
    pt[cur][t][0] = px; pt[cur][t][1] = py; pt[cur][t][2] = pz;
    __syncthreads();
    ureg[bi] = 0; meta[bi] = 0;
    if (owner) {
      // projection; quantize to u16.8 fixed point (floor), pack (y<<16)|x
      float xr = fmaf(rsh_s[bi][0], px, fmaf(rsh_s[bi][1], py, fmaf(rsh_s[bi][2], pz, rsh_s[bi][6])));
      float yr = fmaf(rsh_s[bi][3], px, fmaf(rsh_s[bi][4], py, fmaf(rsh_s[bi][5], pz, rsh_s[bi][7])));
      xr = fminf(fmaxf(xr, 0.0f), 254.999f);
      yr = fminf(fmaxf(yr, 0.0f), 254.999f);
      unsigned xf = (unsigned)(xr * 256.0f);   // <= 65279 -> x0 <= 254
      unsigned yf = (unsigned)(yr * 256.0f);
      unsigned band = yf >> 13;                // row>>5, 0..7
      int rank = atomicAdd(&bcnt[bi][band], 1);
      ureg[bi] = (yf << 16) | xf;
      meta[bi] = ((unsigned)rank << 3) | band;
      // bond length
      if (n < kN - 1) {
        float dx = pt[cur][t + 1][0] - px, dy = pt[cur][t + 1][1] - py,
              dz = pt[cur][t + 1][2] - pz;
        bond[(size_t)b * (kN - 1) + n] =
            sqrtf(fmaf(dx, dx, fmaf(dy, dy, fmaf(dz, dz, 1e-12f))));
      }
      // angle at interior atom n+1 (fast acos, |err| <= 6.7e-5 rad)
      if (n < kN - 2) {
        float mx = pt[cur][t + 1][0], my = pt[cur][t + 1][1], mz = pt[cur][t + 1][2];
        float ux = px - mx, uy = py - my, uz = pz - mz;
        float vx = pt[cur][t + 2][0] - mx, vy = pt[cur][t + 2][1] - my,
              vz = pt[cur][t + 2][2] - mz;
        float uu = fmaf(ux, ux, fmaf(uy, uy, uz * uz));
        float vv = fmaf(vx, vx, fmaf(vy, vy, vz * vz));
        float uv = fmaf(ux, vx, fmaf(uy, vy, uz * vz));
        float cosang = uv * rsqrtf(uu * vv);
        cosang = fminf(fmaxf(cosang, -0.9999f), 0.9999f);
        float ax = fabsf(cosang);
        float rt = sqrtf(1.0f - ax);
        float pp = fmaf(fmaf(fmaf(-0.0187293f, ax, 0.0742610f), ax, -0.2121144f),
                        ax, 1.5707288f);
        float res = rt * pp;
        angle[(size_t)b * (kN - 2) + n] = (cosang >= 0.f) ? res : (float)M_PI - res;
      }
    }
  }
  __syncthreads();
  if (t < kBG * 8) {
    int po = t >> 3, bandx = t & 7;
    int c = bcnt[po][bandx];
    bbase[po][bandx] = c ? atomicAdd(&gcount[(bg + po) * 8 + bandx], c) : 0;
  }
  __syncthreads();
#pragma unroll
  for (int bi = 0; bi < kBG; ++bi) {
    if (owner) {
      unsigned band = meta[bi] & 7;
      int pos = bbase[bi][band] + (int)(meta[bi] >> 3);
      if (pos < kCap) xy_bkt[((size_t)(bg + bi) * 8 + band) * kCap + pos] = ureg[bi];
    }
  }
}

// ---------------------------------------------------------------------------
// Phase B: bilinear splat from per-(pose,band) compact lists into a 33x256
// INTEGER (u18.14 fixed-point) LDS tile via native ds_add_u32 atomics
// (float LDS atomicAdd compiles to a CAS loop without -munsafe-fp-atomics --
// measured ~270 cyc/atomic in round 4). Plain stores out (boundary rows 0/32
// via global float atomics). grid: 32 poses * 8 bands, 1024 threads.
// ---------------------------------------------------------------------------
__global__ __launch_bounds__(1024) void k_splat(const unsigned* __restrict__ xy_bkt,
                                                const int* __restrict__ gcount,
                                                float* __restrict__ img) {
  __shared__ unsigned tile[33 * 256];
  const int t = threadIdx.x;
  const int b = blockIdx.x >> 3;
  const int band = blockIdx.x & 7;
  const int r0 = band * 32;
  for (int i = t; i < 33 * 256; i += 1024) tile[i] = 0u;
  __syncthreads();

  const int c = min(gcount[b * 8 + band], kCap);
  const unsigned* seg = xy_bkt + ((size_t)b * 8 + band) * kCap;

  auto splat1 = [&](unsigned u) {
    int yf = (int)(u >> 16);
    int xf = (int)(u & 0xFFFFu);
    int ry = (yf >> 8) - r0;                 // guaranteed 0..31 by bucketing
    int x0 = xf >> 8;
    int fx = xf & 255, fy = yf & 255;        // u0.8 fractions
    int gx = 256 - fx, gy = 256 - fy;
    int base = ry * 256 + x0;
    // w * 2^14 = (w8a * w8b + 2) >> 2  (round-to-nearest-ish)
    atomicAdd(&tile[base],       (unsigned)((gx * gy + 2) >> 2));
    atomicAdd(&tile[base + 1],   (unsigned)((fx * gy + 2) >> 2));
    atomicAdd(&tile[base + 256], (unsigned)((gx * fy + 2) >> 2));
    atomicAdd(&tile[base + 257], (unsigned)((fx * fy + 2) >> 2));
  };

  // main loop: 4 atoms per thread per iteration (uint4, segment is 16B-aligned)
  const int c4 = c & ~3;
  const uint4* seg4 = reinterpret_cast<const uint4*>(seg);
  for (int i4 = t; i4 * 4 < c4; i4 += 1024) {
    uint4 q = seg4[i4];
    splat1(q.x); splat1(q.y); splat1(q.z); splat1(q.w);
  }
  for (int i = c4 + t; i < c; i += 1024) splat1(seg[i]);
  __syncthreads();

  const int col = t & 255;
  for (int r = (t >> 8); r < 33; r += 4) {
    int row = r0 + r;
    if (row >= kS) continue;                 // band 7 has no row 256
    float v = (float)tile[r * 256 + col] * (1.0f / 16384.0f);
    float* p = img + ((size_t)b * kS + row) * kS + col;
    if (r == 0 || r == 32) unsafeAtomicAdd(p, v);
    else                   *p = v;
  }
}

// ---------------------------------------------------------------------------
// FFT passes. Spectrum lives TRANSPOSED: FcT[b][kx][ky] so the column pass is
// fully coalesced; row passes transpose via LDS in 32B chunks.
// ---------------------------------------------------------------------------
__global__ __launch_bounds__(256) void k_fft_rows_fwd(const float* __restrict__ img,
                                                      float2* __restrict__ FcT) {
  __shared__ float2 smres[4][256];
  __shared__ float2 smtmp[2][256];
  __shared__ float2 tw[128];
  const int t = threadIdx.x, half = t >> 7, lane = t & 127;
  build_tw(tw, t);
  const int b = blockIdx.x >> 6;
  const int y0 = (blockIdx.x & 63) * 4;
  __syncthreads();
#pragma unroll
  for (int q = 0; q < 2; ++q) {
    int j = q * 2 + half;
    const float* row = img + ((size_t)b * kS + y0 + j) * kS;
    float2* a = smres[j];
    a[lane]       = make_float2(row[lane], 0.f);
    a[lane + 128] = make_float2(row[lane + 128], 0.f);
    fft256t<-1>(a, smtmp[half], lane, tw);
  }
  // transpose write: thread t = kx, 4 consecutive ky -> 32B contiguous
  float2 v0 = smres[0][t], v1 = smres[1][t], v2 = smres[2][t], v3 = smres[3][t];
  float4* o = reinterpret_cast<float4*>(FcT + ((size_t)b * kS + t) * kS + y0);
  o[0] = make_float4(v0.x, v0.y, v1.x, v1.y);
  o[1] = make_float4(v2.x, v2.y, v3.x, v3.y);
}

__global__ __launch_bounds__(256) void k_fft_cols(float2* __restrict__ FcT,
                                                  const float* __restrict__ defocus) {
  __shared__ float2 sm[4][256];
  __shared__ float2 tw[128];
  const int t = threadIdx.x, half = t >> 7, lane = t & 127;
  build_tw(tw, t);
  const int c = blockIdx.x * 2 + half;  // global column id in [0, B*256)
  const int b = c >> 8, kx = c & 255;
  float2* col = FcT + (size_t)c * kS;   // contiguous column
  float2* a = sm[half * 2];
  float2* bb = sm[half * 2 + 1];
  __syncthreads();
  a[lane]       = col[lane];
  a[lane + 128] = col[lane + 128];
  float2* r1 = fft256t<-1>(a, bb, lane, tw);

  // apply real filter H(ky,kx) = G * CTF (defocus-dependent per pose)
  const float D = defocus[b];
  const float fxv = (float)(kx < 128 ? kx : kx - 256) * (1.0f / 256.0f);
  const float fx2 = fxv * fxv;
#pragma unroll
  for (int h = 0; h < 2; ++h) {
    int ky = lane + h * 128;
    float fyv = (float)(ky < 128 ? ky : ky - 256) * (1.0f / 256.0f);
    float s2 = fyv * fyv + fx2;
    float G = __expf(-kGauss * s2);
    float chi = kA1 * D * s2 - kA2 * s2 * s2;
    float sn, cn;
    sincosf(chi, &sn, &cn);
    float H = G * (-(kW1 * sn + kQ0 * cn));
    r1[ky].x *= H;
    r1[ky].y *= H;
  }
  float2* r2 = (r1 == a) ? bb : a;
  float2* res = fft256t<1>(r1, r2, lane, tw);
  col[lane]       = res[lane];
  col[lane + 128] = res[lane + 128];
}

__global__ __launch_bounds__(256) void k_fft_rows_inv(const float2* __restrict__ FcT,
                                                      float* __restrict__ out) {
  __shared__ float2 smres[4][256];
  __shared__ float2 smtmp[2][256];
  __shared__ float2 tw[128];
  const int t = threadIdx.x, half = t >> 7, lane = t & 127;
  build_tw(tw, t);
  const int b = blockIdx.x >> 6;
  const int ky0 = (blockIdx.x & 63) * 4;
  // transpose read: thread t = kx, 4 consecutive ky = 32B contiguous
  const float4* ip = reinterpret_cast<const float4*>(FcT + ((size_t)b * kS + t) * kS + ky0);
  float4 w0 = ip[0], w1 = ip[1];
  smres[0][t] = make_float2(w0.x, w0.y);
  smres[1][t] = make_float2(w0.z, w0.w);
  smres[2][t] = make_float2(w1.x, w1.y);
  smres[3][t] = make_float2(w1.z, w1.w);
  __syncthreads();
#pragma unroll
  for (int q = 0; q < 2; ++q) {
    int j = q * 2 + half;
    float2* res = fft256t<1>(smres[j], smtmp[half], lane, tw);
    float* orow = out + ((size_t)b * kS + ky0 + j) * kS;
    orow[lane]       = res[lane].x * (1.0f / 65536.0f);
    orow[lane + 128] = res[lane + 128].x * (1.0f / 65536.0f);
  }
}

// ---------------------------------------------------------------------------
extern "C" void kernel_launch(void* const* d_in, const int* in_sizes, int n_in,
                              void* d_out, int out_size, void* d_ws, size_t ws_size,
                              hipStream_t stream) {
  const float* c_nma        = (const float*)d_in[0];
  const float* delta_euler  = (const float*)d_in[1];
  const float* delta_shifts = (const float*)d_in[2];
  const float* coords       = (const float*)d_in[3];
  const float* basis_x      = (const float*)d_in[4];
  const float* basis_y      = (const float*)d_in[5];
  const float* basis_z      = (const float*)d_in[6];
  const float* euler_base   = (const float*)d_in[7];
  const float* shifts_base  = (const float*)d_in[8];
  const float* defocus      = (const float*)d_in[9];

  float* out = (float*)d_out;
  float* decoded = out;                                   // B*S*S
  float* bond    = out + (size_t)kB * kS * kS;            // B*(N-1)
  float* angle   = bond + (size_t)kB * (kN - 1);          // B*(N-2)

  char* ws = (char*)d_ws;
  const size_t imgBytes = (size_t)kB * kS * kS * sizeof(float);        // 8 MB
  const size_t fctBytes = (size_t)kB * kS * kS * sizeof(float2);       // 16.8 MB
  float*    img    = (float*)ws;                           // [0, 8MB)
  unsigned* xy_bkt = (unsigned*)(ws + imgBytes);           // [8MB, 24MB)   dead after k_splat
  int*      gcount = (int*)(ws + imgBytes + fctBytes);     // [24.8MB, +1KB) dead after k_splat
  float2*   FcT    = (float2*)(ws + imgBytes);             // [8MB, 24.8MB) aliases xy_bkt (after splat)

  hipMemsetAsync(img, 0, imgBytes, stream);
  hipMemsetAsync(gcount, 0, (size_t)kB * 8 * sizeof(int), stream);

  dim3 gd(kNB, kB / kBG);
  k_deform<<<gd, 256, 0, stream>>>(c_nma, delta_euler, delta_shifts, coords,
                                   basis_x, basis_y, basis_z, euler_base,
                                   shifts_base, xy_bkt, gcount, bond, angle);
  k_splat<<<kB * 8, 1024, 0, stream>>>(xy_bkt, gcount, img);
  k_fft_rows_fwd<<<kB * 64, 256, 0, stream>>>(img, FcT);
  k_fft_cols<<<kB * kS / 2, 256, 0, stream>>>(FcT, defocus);
  k_fft_rows_inv<<<kB * 64, 256, 0, stream>>>(FcT, decoded);
}

// Round 7
// 79.968 us; speedup vs baseline: 8.8356x; 1.2545x over previous
//
#include <hip/hip_runtime.h>
#include <math.h>

namespace {
constexpr int kB = 32;
constexpr int kN = 100000;
constexpr int kL = 12;
constexpr int kS = 256;
constexpr int kBG = 8;                      // poses per block in deform kernel
constexpr int kTile = 254;                  // atoms OWNED per block (2 halo threads)
constexpr int kNB = (kN + kTile - 1) / kTile;  // 394 atom-blocks
constexpr int kCap = 16384;                 // per-(pose,band) bucket capacity
constexpr int kKx = 130;                    // stored kx columns (129 used + pad)

constexpr float kGauss = (float)(2.0 * M_PI * M_PI);                         // 2(pi*sigma)^2, sigma=1
constexpr float kA1 = (float)(M_PI * 0.0197);                                // pi*lambda
constexpr float kA2 = (float)(0.5 * M_PI * 2.7e7 * 0.0197 * 0.0197 * 0.0197);// 0.5*pi*Cs*lambda^3
constexpr float kW1 = 0.99498743710661995f;                                  // sqrt(1-Q0^2)
constexpr float kQ0 = 0.1f;
}

// ---------------------------------------------------------------------------
// 256-point Stockham radix-2 FFT in LDS with a shared twiddle table.
// 128 lanes per FFT, 8 stages, auto-sorting. Result ends in buffer `a`.
// tw[k] = (cos, sin)(pi*k/128); SIGN=-1 forward, +1 inverse.
// Contains __syncthreads(): all 256 threads of the block must call uniformly.
// ---------------------------------------------------------------------------
template <int SIGN>
__device__ __forceinline__ float2* fft256t(float2* a, float2* b, int lane,
                                           const float2* tw) {
#pragma unroll
  for (int m = 1; m <= 128; m <<= 1) {
    float2 c0 = a[lane];
    float2 c1 = a[lane + 128];
    int jm = lane & ~(m - 1);
    float2 w = tw[jm];
    float c = w.x;
    float s = (SIGN < 0) ? -w.y : w.y;
    float ex = c0.x + c1.x, ey = c0.y + c1.y;
    float dx = c0.x - c1.x, dy = c0.y - c1.y;
    b[lane + jm]     = make_float2(ex, ey);
    b[lane + jm + m] = make_float2(c * dx - s * dy, c * dy + s * dx);
    __syncthreads();
    float2* tp = a; a = b; b = tp;
  }
  return a;  // 8 swaps -> result back in original `a` buffer
}

__device__ __forceinline__ void build_tw(float2* tw, int t) {
  if (t < 128) {
    float s, c;
    sincosf((float)M_PI / 128.0f * (float)t, &s, &c);
    tw[t] = make_float2(c, s);
  }
}

// ---------------------------------------------------------------------------
// Phase A: deformation -> bond, angle, projected (x,y) packed u16.8 into
// per-(pose, 32-row band) compact bucket lists. (unchanged from round 6)
// ---------------------------------------------------------------------------
__global__ __launch_bounds__(256) void k_deform(
    const float* __restrict__ c_nma, const float* __restrict__ delta_euler,
    const float* __restrict__ delta_shifts, const float* __restrict__ coords,
    const float* __restrict__ basis_x, const float* __restrict__ basis_y,
    const float* __restrict__ basis_z, const float* __restrict__ euler_base,
    const float* __restrict__ shifts_base,
    unsigned* __restrict__ xy_bkt, int* __restrict__ gcount,
    float* __restrict__ bond, float* __restrict__ angle) {
  __shared__ float cn_s[kBG][kL];
  __shared__ float rsh_s[kBG][8];
  __shared__ float pt[2][256][3];
  __shared__ int bcnt[kBG][8];
  __shared__ int bbase[kBG][8];

  const int t = threadIdx.x;
  const int n0 = blockIdx.x * kTile;
  const int bg = blockIdx.y * kBG;
  const int n = n0 + t;
  const bool valid = n < kN;                    // thread has an atom (incl halo)
  const bool owner = (t < kTile) && valid;      // thread writes outputs

  if (t < kBG * kL) cn_s[t / kL][t % kL] = c_nma[(bg + t / kL) * kL + (t % kL)];
  if (t < kBG) {
    int b = bg + t;
    float rot  = euler_base[b * 3 + 0] + delta_euler[b * 3 + 0];
    float tilt = euler_base[b * 3 + 1] + delta_euler[b * 3 + 1];
    float psi  = euler_base[b * 3 + 2] + delta_euler[b * 3 + 2];
    float ca = cosf(rot), sa = sinf(rot);
    float cb = cosf(tilt), sb = sinf(tilt);
    float cg = cosf(psi), sg = sinf(psi);
    rsh_s[t][0] = cg * cb * ca - sg * sa;
    rsh_s[t][1] = cg * cb * sa + sg * ca;
    rsh_s[t][2] = -cg * sb;
    rsh_s[t][3] = -sg * cb * ca - cg * sa;
    rsh_s[t][4] = -sg * cb * sa + cg * ca;
    rsh_s[t][5] = sg * sb;
    rsh_s[t][6] = shifts_base[b * 2 + 0] + delta_shifts[b * 2 + 0] + 128.0f;
    rsh_s[t][7] = shifts_base[b * 2 + 1] + delta_shifts[b * 2 + 1] + 128.0f;
  }
  if (t < kBG * 8) bcnt[t >> 3][t & 7] = 0;

  float cx = 0.f, cy = 0.f, cz = 0.f;
  float bx[kL], by[kL], bz[kL];
#pragma unroll
  for (int l = 0; l < kL; ++l) { bx[l] = 0.f; by[l] = 0.f; bz[l] = 0.f; }
  if (valid) {
    cx = coords[n * 3 + 0]; cy = coords[n * 3 + 1]; cz = coords[n * 3 + 2];
    const float4* px4 = reinterpret_cast<const float4*>(basis_x + (size_t)n * kL);
    const float4* py4 = reinterpret_cast<const float4*>(basis_y + (size_t)n * kL);
    const float4* pz4 = reinterpret_cast<const float4*>(basis_z + (size_t)n * kL);
#pragma unroll
    for (int q = 0; q < 3; ++q) {
      float4 vx = px4[q], vy = py4[q], vz = pz4[q];
      bx[q * 4 + 0] = vx.x; bx[q * 4 + 1] = vx.y; bx[q * 4 + 2] = vx.z; bx[q * 4 + 3] = vx.w;
      by[q * 4 + 0] = vy.x; by[q * 4 + 1] = vy.y; by[q * 4 + 2] = vy.z; by[q * 4 + 3] = vy.w;
      bz[q * 4 + 0] = vz.x; bz[q * 4 + 1] = vz.y; bz[q * 4 + 2] = vz.z; bz[q * 4 + 3] = vz.w;
    }
  }
  __syncthreads();

  unsigned ureg[kBG];   // packed (y<<16)|x per pose
  unsigned meta[kBG];   // (rank<<3)|band per pose

#pragma unroll
  for (int bi = 0; bi < kBG; ++bi) {
    const int cur = bi & 1;
    const int b = bg + bi;
    float px = cx, py = cy, pz = cz;
#pragma unroll
    for (int l = 0; l < kL; ++l) {
      float cc = cn_s[bi][l];
      px = fmaf(cc, bx[l], px);
      py = fmaf(cc, by[l], py);
      pz = fmaf(cc, bz[l], pz);
    }
    pt[cur][t][0] = px; pt[cur][t][1] = py; pt[cur][t][2] = pz;
    __syncthreads();
    ureg[bi] = 0; meta[bi] = 0;
    if (owner) {
      // projection; quantize to u16.8 fixed point (floor), pack (y<<16)|x
      float xr = fmaf(rsh_s[bi][0], px, fmaf(rsh_s[bi][1], py, fmaf(rsh_s[bi][2], pz, rsh_s[bi][6])));
      float yr = fmaf(rsh_s[bi][3], px, fmaf(rsh_s[bi][4], py, fmaf(rsh_s[bi][5], pz, rsh_s[bi][7])));
      xr = fminf(fmaxf(xr, 0.0f), 254.999f);
      yr = fminf(fmaxf(yr, 0.0f), 254.999f);
      unsigned xf = (unsigned)(xr * 256.0f);   // <= 65279 -> x0 <= 254
      unsigned yf = (unsigned)(yr * 256.0f);
      unsigned band = yf >> 13;                // row>>5, 0..7
      int rank = atomicAdd(&bcnt[bi][band], 1);
      ureg[bi] = (yf << 16) | xf;
      meta[bi] = ((unsigned)rank << 3) | band;
      // bond length
      if (n < kN - 1) {
        float dx = pt[cur][t + 1][0] - px, dy = pt[cur][t + 1][1] - py,
              dz = pt[cur][t + 1][2] - pz;
        bond[(size_t)b * (kN - 1) + n] =
            sqrtf(fmaf(dx, dx, fmaf(dy, dy, fmaf(dz, dz, 1e-12f))));
      }
      // angle at interior atom n+1 (fast acos, |err| <= 6.7e-5 rad)
      if (n < kN - 2) {
        float mx = pt[cur][t + 1][0], my = pt[cur][t + 1][1], mz = pt[cur][t + 1][2];
        float ux = px - mx, uy = py - my, uz = pz - mz;
        float vx = pt[cur][t + 2][0] - mx, vy = pt[cur][t + 2][1] - my,
              vz = pt[cur][t + 2][2] - mz;
        float uu = fmaf(ux, ux, fmaf(uy, uy, uz * uz));
        float vv = fmaf(vx, vx, fmaf(vy, vy, vz * vz));
        float uv = fmaf(ux, vx, fmaf(uy, vy, uz * vz));
        float cosang = uv * rsqrtf(uu * vv);
        cosang = fminf(fmaxf(cosang, -0.9999f), 0.9999f);
        float ax = fabsf(cosang);
        float rt = sqrtf(1.0f - ax);
        float pp = fmaf(fmaf(fmaf(-0.0187293f, ax, 0.0742610f), ax, -0.2121144f),
                        ax, 1.5707288f);
        float res = rt * pp;
        angle[(size_t)b * (kN - 2) + n] = (cosang >= 0.f) ? res : (float)M_PI - res;
      }
    }
  }
  __syncthreads();
  if (t < kBG * 8) {
    int po = t >> 3, bandx = t & 7;
    int c = bcnt[po][bandx];
    bbase[po][bandx] = c ? atomicAdd(&gcount[(bg + po) * 8 + bandx], c) : 0;
  }
  __syncthreads();
#pragma unroll
  for (int bi = 0; bi < kBG; ++bi) {
    if (owner) {
      unsigned band = meta[bi] & 7;
      int pos = bbase[bi][band] + (int)(meta[bi] >> 3);
      if (pos < kCap) xy_bkt[((size_t)(bg + bi) * 8 + band) * kCap + pos] = ureg[bi];
    }
  }
}

// ---------------------------------------------------------------------------
// Phase B: bilinear splat from per-(pose,band) compact lists into a 33x256
// INTEGER (u18.14) LDS tile via native ds_add_u32. ALL outputs are plain
// stores now: rows 0..31 -> img; the r=32 overflow row -> bnd[b][band][256]
// (added back at FFT-load time). img needs NO zero-init.
// grid: 32 poses * 8 bands, 1024 threads.
// ---------------------------------------------------------------------------
__global__ __launch_bounds__(1024) void k_splat(const unsigned* __restrict__ xy_bkt,
                                                const int* __restrict__ gcount,
                                                float* __restrict__ img,
                                                float* __restrict__ bnd) {
  __shared__ unsigned tile[33 * 256];
  const int t = threadIdx.x;
  const int b = blockIdx.x >> 3;
  const int band = blockIdx.x & 7;
  const int r0 = band * 32;
  for (int i = t; i < 33 * 256; i += 1024) tile[i] = 0u;
  __syncthreads();

  const int c = min(gcount[b * 8 + band], kCap);
  const unsigned* seg = xy_bkt + ((size_t)b * 8 + band) * kCap;

  auto splat1 = [&](unsigned u) {
    int yf = (int)(u >> 16);
    int xf = (int)(u & 0xFFFFu);
    int ry = (yf >> 8) - r0;                 // guaranteed 0..31 by bucketing
    int x0 = xf >> 8;
    int fx = xf & 255, fy = yf & 255;        // u0.8 fractions
    int gx = 256 - fx, gy = 256 - fy;
    int base = ry * 256 + x0;
    // w * 2^14 = (w8a * w8b + 2) >> 2  (round-to-nearest-ish)
    atomicAdd(&tile[base],       (unsigned)((gx * gy + 2) >> 2));
    atomicAdd(&tile[base + 1],   (unsigned)((fx * gy + 2) >> 2));
    atomicAdd(&tile[base + 256], (unsigned)((gx * fy + 2) >> 2));
    atomicAdd(&tile[base + 257], (unsigned)((fx * fy + 2) >> 2));
  };

  const int c4 = c & ~3;
  const uint4* seg4 = reinterpret_cast<const uint4*>(seg);
  for (int i4 = t; i4 * 4 < c4; i4 += 1024) {
    uint4 q = seg4[i4];
    splat1(q.x); splat1(q.y); splat1(q.z); splat1(q.w);
  }
  for (int i = c4 + t; i < c; i += 1024) splat1(seg[i]);
  __syncthreads();

  const int col = t & 255;
  for (int r = (t >> 8); r < 33; r += 4) {
    float v = (float)tile[r * 256 + col] * (1.0f / 16384.0f);
    if (r < 32)          img[((size_t)b * kS + r0 + r) * kS + col] = v;
    else if (band < 7)   bnd[((size_t)b * 7 + band) * kS + col] = v;
  }
}

// ---------------------------------------------------------------------------
// FFT passes with real-FFT packing (2 real rows per complex FFT) and
// Hermitian-reduced spectrum: only kx = 0..128 stored, TRANSPOSED:
// FcT[b][kx][y], kx-stride kKx=130.
// ---------------------------------------------------------------------------
__global__ __launch_bounds__(256) void k_fft_rows_fwd(const float* __restrict__ img,
                                                      const float* __restrict__ bnd,
                                                      float2* __restrict__ FcT) {
  __shared__ float2 smA[2][256];
  __shared__ float2 smB[2][256];
  __shared__ float2 tw[128];
  const int t = threadIdx.x, half = t >> 7, lane = t & 127;
  build_tw(tw, t);
  const int b = blockIdx.x >> 6;
  const int y0 = (blockIdx.x & 63) * 4;

  // pack rows (y0+2h, y0+2h+1) as re+i*im; add band-overflow to rows %32==0
  const float* rA = img + ((size_t)b * kS + y0 + 2 * half) * kS;
  const float* rB = rA + kS;
  float eA0 = 0.f, eA1 = 0.f;
  if (half == 0 && y0 != 0 && (y0 & 31) == 0) {
    const float* bp = bnd + ((size_t)b * 7 + (y0 >> 5) - 1) * kS;
    eA0 = bp[lane]; eA1 = bp[lane + 128];
  }
  float2* a = smA[half];
  a[lane]       = make_float2(rA[lane] + eA0,       rB[lane]);
  a[lane + 128] = make_float2(rA[lane + 128] + eA1, rB[lane + 128]);
  __syncthreads();
  fft256t<-1>(a, smB[half], lane, tw);   // result in smA[half]

  // unpack 4 row-spectra at k=t (t<=128) and transpose-write 32B chunks
  if (t <= 128) {
    int tm = (256 - t) & 255;
    float2 Zk0 = smA[0][t], Zm0 = smA[0][tm];
    float2 Zk1 = smA[1][t], Zm1 = smA[1][tm];
    float4 o0 = make_float4(0.5f * (Zk0.x + Zm0.x), 0.5f * (Zk0.y - Zm0.y),
                            0.5f * (Zk0.y + Zm0.y), 0.5f * (Zm0.x - Zk0.x));
    float4 o1 = make_float4(0.5f * (Zk1.x + Zm1.x), 0.5f * (Zk1.y - Zm1.y),
                            0.5f * (Zk1.y + Zm1.y), 0.5f * (Zm1.x - Zk1.x));
    float4* o = reinterpret_cast<float4*>(FcT + ((size_t)b * kKx + t) * kS + y0);
    o[0] = o0;
    o[1] = o1;
  }
}

__global__ __launch_bounds__(256) void k_fft_cols(float2* __restrict__ FcT,
                                                  const float* __restrict__ defocus) {
  __shared__ float2 sm[4][256];
  __shared__ float2 tw[128];
  const int t = threadIdx.x, half = t >> 7, lane = t & 127;
  build_tw(tw, t);
  const int b = blockIdx.x / 65, kxp = blockIdx.x % 65;
  const int kx = kxp * 2 + half;          // 0..129; 129 is duplicate work
  const int kxr = min(kx, 128);
  float2* col = FcT + ((size_t)b * kKx + kxr) * kS;   // contiguous column
  float2* a = sm[half * 2];
  float2* bb = sm[half * 2 + 1];
  __syncthreads();
  a[lane]       = col[lane];
  a[lane + 128] = col[lane + 128];
  float2* r1 = fft256t<-1>(a, bb, lane, tw);

  // apply real filter H(ky,kx) = G * CTF (defocus-dependent per pose)
  const float D = defocus[b];
  const float fxv = (float)kxr * (1.0f / 256.0f);     // rfftfreq: 0..0.5
  const float fx2 = fxv * fxv;
#pragma unroll
  for (int h = 0; h < 2; ++h) {
    int ky = lane + h * 128;
    float fyv = (float)(ky < 128 ? ky : ky - 256) * (1.0f / 256.0f);
    float s2 = fyv * fyv + fx2;
    float G = __expf(-kGauss * s2);
    float chi = kA1 * D * s2 - kA2 * s2 * s2;
    float sn, cn;
    sincosf(chi, &sn, &cn);
    float H = G * (-(kW1 * sn + kQ0 * cn));
    r1[ky].x *= H;
    r1[ky].y *= H;
  }
  float2* r2 = (r1 == a) ? bb : a;
  float2* res = fft256t<1>(r1, r2, lane, tw);
  if (kx <= 128) {
    col[lane]       = res[lane];
    col[lane + 128] = res[lane + 128];
  }
}

__global__ __launch_bounds__(256) void k_fft_rows_inv(const float2* __restrict__ FcT,
                                                      float* __restrict__ out) {
  __shared__ float2 smA[2][256];
  __shared__ float2 smB[2][256];
  __shared__ float2 smT[130 * 5];          // [k][r], stride 5 to spread banks
  __shared__ float2 tw[128];
  const int t = threadIdx.x, half = t >> 7, lane = t & 127;
  build_tw(tw, t);
  const int b = blockIdx.x >> 6;
  const int y0 = (blockIdx.x & 63) * 4;

  // stage T(k, y0..y0+3), k = 0..128 (transpose read, 32B chunks)
  if (t < 129) {
    const float4* ip =
        reinterpret_cast<const float4*>(FcT + ((size_t)b * kKx + t) * kS + y0);
    float4 w0 = ip[0], w1 = ip[1];
    smT[t * 5 + 0] = make_float2(w0.x, w0.y);
    smT[t * 5 + 1] = make_float2(w0.z, w0.w);
    smT[t * 5 + 2] = make_float2(w1.x, w1.y);
    smT[t * 5 + 3] = make_float2(w1.z, w1.w);
  }
  __syncthreads();

  // build Z(k) = T1(k) + i*T2(k) with Hermitian extension for k>128
  float2* a = smA[half];
  {
    float2 T1 = smT[lane * 5 + 2 * half], T2 = smT[lane * 5 + 2 * half + 1];
    a[lane] = make_float2(T1.x - T2.y, T1.y + T2.x);
    int km = (lane == 0) ? 128 : (128 - lane);
    float2 T1m = smT[km * 5 + 2 * half], T2m = smT[km * 5 + 2 * half + 1];
    a[lane + 128] = (lane == 0)
        ? make_float2(T1m.x - T2m.y, T1m.y + T2m.x)
        : make_float2(T1m.x + T2m.y, -T1m.y + T2m.x);
  }
  __syncthreads();
  float2* res = fft256t<1>(a, smB[half], lane, tw);  // rows y0+2h, y0+2h+1

  float* o0 = out + ((size_t)b * kS + y0 + 2 * half) * kS;
  float* o1 = o0 + kS;
  o0[lane]       = res[lane].x * (1.0f / 65536.0f);
  o0[lane + 128] = res[lane + 128].x * (1.0f / 65536.0f);
  o1[lane]       = res[lane].y * (1.0f / 65536.0f);
  o1[lane + 128] = res[lane + 128].y * (1.0f / 65536.0f);
}

// ---------------------------------------------------------------------------
extern "C" void kernel_launch(void* const* d_in, const int* in_sizes, int n_in,
                              void* d_out, int out_size, void* d_ws, size_t ws_size,
                              hipStream_t stream) {
  const float* c_nma        = (const float*)d_in[0];
  const float* delta_euler  = (const float*)d_in[1];
  const float* delta_shifts = (const float*)d_in[2];
  const float* coords       = (const float*)d_in[3];
  const float* basis_x      = (const float*)d_in[4];
  const float* basis_y      = (const float*)d_in[5];
  const float* basis_z      = (const float*)d_in[6];
  const float* euler_base   = (const float*)d_in[7];
  const float* shifts_base  = (const float*)d_in[8];
  const float* defocus      = (const float*)d_in[9];

  float* out = (float*)d_out;
  float* decoded = out;                                   // B*S*S
  float* bond    = out + (size_t)kB * kS * kS;            // B*(N-1)
  float* angle   = bond + (size_t)kB * (kN - 1);          // B*(N-2)

  char* ws = (char*)d_ws;
  const size_t imgBytes = (size_t)kB * kS * kS * sizeof(float);        // 8 MB
  float*    img    = (float*)ws;                           // [0, 8MB)
  unsigned* xy_bkt = (unsigned*)(ws + imgBytes);           // [8MB, 24MB) dead after k_splat
  float2*   FcT    = (float2*)(ws + imgBytes);             // [8MB, 16.5MB) aliases xy_bkt (after splat)
  int*      gcount = (int*)(ws + imgBytes + (size_t)17 * 1024 * 1024);  // [25MB, +1KB)
  float*    bnd    = (float*)(ws + imgBytes + (size_t)18 * 1024 * 1024);// [26MB, +229KB)

  hipMemsetAsync(gcount, 0, (size_t)kB * 8 * sizeof(int), stream);

  dim3 gd(kNB, kB / kBG);
  k_deform<<<gd, 256, 0, stream>>>(c_nma, delta_euler, delta_shifts, coords,
                                   basis_x, basis_y, basis_z, euler_base,
                                   shifts_base, xy_bkt, gcount, bond, angle);
  k_splat<<<kB * 8, 1024, 0, stream>>>(xy_bkt, gcount, img, bnd);
  k_fft_rows_fwd<<<kB * 64, 256, 0, stream>>>(img, bnd, FcT);
  k_fft_cols<<<kB * 65, 256, 0, stream>>>(FcT, defocus);
  k_fft_rows_inv<<<kB * 64, 256, 0, stream>>>(FcT, decoded);
}

// Round 8
// 75.416 us; speedup vs baseline: 9.3690x; 1.0604x over previous
//
#include <hip/hip_runtime.h>
#include <math.h>

namespace {
constexpr int kB = 32;
constexpr int kN = 100000;
constexpr int kL = 12;
constexpr int kS = 256;
constexpr int kBG = 8;                      // poses per block in deform kernel
constexpr int kWOwn = 62;                   // atoms OWNED per wave (2 shuffle-halo lanes)
constexpr int kTile = 4 * kWOwn;            // 248 atoms owned per 256-thread block
constexpr int kNB = (kN + kTile - 1) / kTile;  // 404 atom-blocks
constexpr int kCap = 16384;                 // per-(pose,band) bucket capacity
constexpr int kKx = 130;                    // stored kx columns (129 used + pad)

constexpr float kGauss = (float)(2.0 * M_PI * M_PI);                         // 2(pi*sigma)^2, sigma=1
constexpr float kA1 = (float)(M_PI * 0.0197);                                // pi*lambda
constexpr float kA2 = (float)(0.5 * M_PI * 2.7e7 * 0.0197 * 0.0197 * 0.0197);// 0.5*pi*Cs*lambda^3
constexpr float kW1 = 0.99498743710661995f;                                  // sqrt(1-Q0^2)
constexpr float kQ0 = 0.1f;
}

// ---------------------------------------------------------------------------
// 256-point Stockham radix-2 FFT in LDS with a shared twiddle table.
// 128 lanes per FFT, 8 stages, auto-sorting. Result ends in buffer `a`.
// tw[k] = (cos, sin)(pi*k/128); SIGN=-1 forward, +1 inverse.
// Contains __syncthreads(): all 256 threads of the block must call uniformly.
// ---------------------------------------------------------------------------
template <int SIGN>
__device__ __forceinline__ float2* fft256t(float2* a, float2* b, int lane,
                                           const float2* tw) {
#pragma unroll
  for (int m = 1; m <= 128; m <<= 1) {
    float2 c0 = a[lane];
    float2 c1 = a[lane + 128];
    int jm = lane & ~(m - 1);
    float2 w = tw[jm];
    float c = w.x;
    float s = (SIGN < 0) ? -w.y : w.y;
    float ex = c0.x + c1.x, ey = c0.y + c1.y;
    float dx = c0.x - c1.x, dy = c0.y - c1.y;
    b[lane + jm]     = make_float2(ex, ey);
    b[lane + jm + m] = make_float2(c * dx - s * dy, c * dy + s * dx);
    __syncthreads();
    float2* tp = a; a = b; b = tp;
  }
  return a;  // 8 swaps -> result back in original `a` buffer
}

__device__ __forceinline__ void build_tw(float2* tw, int t) {
  if (t < 128) {
    float s, c;
    sincosf((float)M_PI / 128.0f * (float)t, &s, &c);
    tw[t] = make_float2(c, s);
  }
}

// ---------------------------------------------------------------------------
// Phase A: deformation -> bond, angle, projected (x,y) packed u16.8 into
// per-(pose, 32-row band) compact bucket lists.
// Wave w owns atoms [blk*248 + w*62, +62); all 64 lanes compute (2 halo
// lanes), neighbors p[n+1]/p[n+2] come from __shfl_down -- NO barrier in the
// pose loop and no pt[] LDS. Loads clamp to atom kN-1 (the clamped duplicate
// IS the correct neighbor at the chain end). Batched reservation at the end.
// ---------------------------------------------------------------------------
__global__ __launch_bounds__(256) void k_deform(
    const float* __restrict__ c_nma, const float* __restrict__ delta_euler,
    const float* __restrict__ delta_shifts, const float* __restrict__ coords,
    const float* __restrict__ basis_x, const float* __restrict__ basis_y,
    const float* __restrict__ basis_z, const float* __restrict__ euler_base,
    const float* __restrict__ shifts_base,
    unsigned* __restrict__ xy_bkt, int* __restrict__ gcount,
    float* __restrict__ bond, float* __restrict__ angle) {
  __shared__ float cn_s[kBG][kL];
  __shared__ float rsh_s[kBG][8];
  __shared__ int bcnt[kBG][8];
  __shared__ int bbase[kBG][8];

  const int t = threadIdx.x;
  const int wave = t >> 6, lane = t & 63;
  const int bg = blockIdx.y * kBG;
  const int n = blockIdx.x * kTile + wave * kWOwn + lane;
  const bool owner = (lane < kWOwn) && (n < kN);
  const int nc = min(n, kN - 1);

  if (t < kBG * kL) cn_s[t / kL][t % kL] = c_nma[(bg + t / kL) * kL + (t % kL)];
  if (t < kBG) {
    int b = bg + t;
    float rot  = euler_base[b * 3 + 0] + delta_euler[b * 3 + 0];
    float tilt = euler_base[b * 3 + 1] + delta_euler[b * 3 + 1];
    float psi  = euler_base[b * 3 + 2] + delta_euler[b * 3 + 2];
    float ca = cosf(rot), sa = sinf(rot);
    float cb = cosf(tilt), sb = sinf(tilt);
    float cg = cosf(psi), sg = sinf(psi);
    rsh_s[t][0] = cg * cb * ca - sg * sa;
    rsh_s[t][1] = cg * cb * sa + sg * ca;
    rsh_s[t][2] = -cg * sb;
    rsh_s[t][3] = -sg * cb * ca - cg * sa;
    rsh_s[t][4] = -sg * cb * sa + cg * ca;
    rsh_s[t][5] = sg * sb;
    rsh_s[t][6] = shifts_base[b * 2 + 0] + delta_shifts[b * 2 + 0] + 128.0f;
    rsh_s[t][7] = shifts_base[b * 2 + 1] + delta_shifts[b * 2 + 1] + 128.0f;
  }
  if (t < kBG * 8) bcnt[t >> 3][t & 7] = 0;

  const float cx = coords[nc * 3 + 0];
  const float cy = coords[nc * 3 + 1];
  const float cz = coords[nc * 3 + 2];
  float bx[kL], by[kL], bz[kL];
  {
    const float4* px4 = reinterpret_cast<const float4*>(basis_x + (size_t)nc * kL);
    const float4* py4 = reinterpret_cast<const float4*>(basis_y + (size_t)nc * kL);
    const float4* pz4 = reinterpret_cast<const float4*>(basis_z + (size_t)nc * kL);
#pragma unroll
    for (int q = 0; q < 3; ++q) {
      float4 vx = px4[q], vy = py4[q], vz = pz4[q];
      bx[q * 4 + 0] = vx.x; bx[q * 4 + 1] = vx.y; bx[q * 4 + 2] = vx.z; bx[q * 4 + 3] = vx.w;
      by[q * 4 + 0] = vy.x; by[q * 4 + 1] = vy.y; by[q * 4 + 2] = vy.z; by[q * 4 + 3] = vy.w;
      bz[q * 4 + 0] = vz.x; bz[q * 4 + 1] = vz.y; bz[q * 4 + 2] = vz.z; bz[q * 4 + 3] = vz.w;
    }
  }
  __syncthreads();

  unsigned ureg[kBG];   // packed (y<<16)|x per pose
  unsigned meta[kBG];   // (rank<<3)|band per pose

#pragma unroll
  for (int bi = 0; bi < kBG; ++bi) {
    const int b = bg + bi;
    float px = cx, py = cy, pz = cz;
#pragma unroll
    for (int l = 0; l < kL; ++l) {
      float cc = cn_s[bi][l];
      px = fmaf(cc, bx[l], px);
      py = fmaf(cc, by[l], py);
      pz = fmaf(cc, bz[l], pz);
    }
    // neighbors via wave shuffles (lanes 62/63 receive garbage; non-owners)
    float p1x = __shfl_down(px, 1), p1y = __shfl_down(py, 1), p1z = __shfl_down(pz, 1);
    float p2x = __shfl_down(p1x, 1), p2y = __shfl_down(p1y, 1), p2z = __shfl_down(p1z, 1);

    ureg[bi] = 0; meta[bi] = 0;
    if (owner) {
      // projection; quantize to u16.8 fixed point (floor), pack (y<<16)|x
      float xr = fmaf(rsh_s[bi][0], px, fmaf(rsh_s[bi][1], py, fmaf(rsh_s[bi][2], pz, rsh_s[bi][6])));
      float yr = fmaf(rsh_s[bi][3], px, fmaf(rsh_s[bi][4], py, fmaf(rsh_s[bi][5], pz, rsh_s[bi][7])));
      xr = fminf(fmaxf(xr, 0.0f), 254.999f);
      yr = fminf(fmaxf(yr, 0.0f), 254.999f);
      unsigned xf = (unsigned)(xr * 256.0f);   // <= 65279 -> x0 <= 254
      unsigned yf = (unsigned)(yr * 256.0f);
      unsigned band = yf >> 13;                // row>>5, 0..7
      int rank = atomicAdd(&bcnt[bi][band], 1);
      ureg[bi] = (yf << 16) | xf;
      meta[bi] = ((unsigned)rank << 3) | band;
      // bond length at n (atoms n, n+1)
      if (n < kN - 1) {
        float dx = p1x - px, dy = p1y - py, dz = p1z - pz;
        bond[(size_t)b * (kN - 1) + n] =
            sqrtf(fmaf(dx, dx, fmaf(dy, dy, fmaf(dz, dz, 1e-12f))));
      }
      // angle at interior atom n+1 (atoms n, n+1, n+2); fast acos
      if (n < kN - 2) {
        float ux = px - p1x, uy = py - p1y, uz = pz - p1z;
        float vx = p2x - p1x, vy = p2y - p1y, vz = p2z - p1z;
        float uu = fmaf(ux, ux, fmaf(uy, uy, uz * uz));
        float vv = fmaf(vx, vx, fmaf(vy, vy, vz * vz));
        float uv = fmaf(ux, vx, fmaf(uy, vy, uz * vz));
        float cosang = uv * rsqrtf(uu * vv);
        cosang = fminf(fmaxf(cosang, -0.9999f), 0.9999f);
        float ax = fabsf(cosang);
        float rt = sqrtf(1.0f - ax);
        float pp = fmaf(fmaf(fmaf(-0.0187293f, ax, 0.0742610f), ax, -0.2121144f),
                        ax, 1.5707288f);
        float res = rt * pp;
        angle[(size_t)b * (kN - 2) + n] = (cosang >= 0.f) ? res : (float)M_PI - res;
      }
    }
  }
  __syncthreads();
  if (t < kBG * 8) {
    int po = t >> 3, bandx = t & 7;
    int c = bcnt[po][bandx];
    bbase[po][bandx] = c ? atomicAdd(&gcount[(bg + po) * 8 + bandx], c) : 0;
  }
  __syncthreads();
#pragma unroll
  for (int bi = 0; bi < kBG; ++bi) {
    if (owner) {
      unsigned band = meta[bi] & 7;
      int pos = bbase[bi][band] + (int)(meta[bi] >> 3);
      if (pos < kCap) xy_bkt[((size_t)(bg + bi) * 8 + band) * kCap + pos] = ureg[bi];
    }
  }
}

// ---------------------------------------------------------------------------
// Phase B: bilinear splat from per-(pose,band) compact lists into a 33x256
// INTEGER (u18.14) LDS tile via native ds_add_u32. ALL outputs are plain
// stores: rows 0..31 -> img; r=32 overflow -> bnd[b][band][256] (added back
// at FFT-load time). img needs NO zero-init. grid: 32*8, 1024 threads.
// ---------------------------------------------------------------------------
__global__ __launch_bounds__(1024) void k_splat(const unsigned* __restrict__ xy_bkt,
                                                const int* __restrict__ gcount,
                                                float* __restrict__ img,
                                                float* __restrict__ bnd) {
  __shared__ unsigned tile[33 * 256];
  const int t = threadIdx.x;
  const int b = blockIdx.x >> 3;
  const int band = blockIdx.x & 7;
  const int r0 = band * 32;
  for (int i = t; i < 33 * 256; i += 1024) tile[i] = 0u;
  __syncthreads();

  const int c = min(gcount[b * 8 + band], kCap);
  const unsigned* seg = xy_bkt + ((size_t)b * 8 + band) * kCap;

  auto splat1 = [&](unsigned u) {
    int yf = (int)(u >> 16);
    int xf = (int)(u & 0xFFFFu);
    int ry = (yf >> 8) - r0;                 // guaranteed 0..31 by bucketing
    int x0 = xf >> 8;
    int fx = xf & 255, fy = yf & 255;        // u0.8 fractions
    int gx = 256 - fx, gy = 256 - fy;
    int base = ry * 256 + x0;
    // w * 2^14 = (w8a * w8b + 2) >> 2  (round-to-nearest-ish)
    atomicAdd(&tile[base],       (unsigned)((gx * gy + 2) >> 2));
    atomicAdd(&tile[base + 1],   (unsigned)((fx * gy + 2) >> 2));
    atomicAdd(&tile[base + 256], (unsigned)((gx * fy + 2) >> 2));
    atomicAdd(&tile[base + 257], (unsigned)((fx * fy + 2) >> 2));
  };

  const int c4 = c & ~3;
  const uint4* seg4 = reinterpret_cast<const uint4*>(seg);
  for (int i4 = t; i4 * 4 < c4; i4 += 1024) {
    uint4 q = seg4[i4];
    splat1(q.x); splat1(q.y); splat1(q.z); splat1(q.w);
  }
  for (int i = c4 + t; i < c; i += 1024) splat1(seg[i]);
  __syncthreads();

  const int col = t & 255;
  for (int r = (t >> 8); r < 33; r += 4) {
    float v = (float)tile[r * 256 + col] * (1.0f / 16384.0f);
    if (r < 32)          img[((size_t)b * kS + r0 + r) * kS + col] = v;
    else if (band < 7)   bnd[((size_t)b * 7 + band) * kS + col] = v;
  }
}

// ---------------------------------------------------------------------------
// FFT passes with real-FFT packing (2 real rows per complex FFT) and
// Hermitian-reduced spectrum: only kx = 0..128 stored, TRANSPOSED:
// FcT[b][kx][y], kx-stride kKx=130.
// ---------------------------------------------------------------------------
__global__ __launch_bounds__(256) void k_fft_rows_fwd(const float* __restrict__ img,
                                                      const float* __restrict__ bnd,
                                                      float2* __restrict__ FcT) {
  __shared__ float2 smA[2][256];
  __shared__ float2 smB[2][256];
  __shared__ float2 tw[128];
  const int t = threadIdx.x, half = t >> 7, lane = t & 127;
  build_tw(tw, t);
  const int b = blockIdx.x >> 6;
  const int y0 = (blockIdx.x & 63) * 4;

  // pack rows (y0+2h, y0+2h+1) as re+i*im; add band-overflow to rows %32==0
  const float* rA = img + ((size_t)b * kS + y0 + 2 * half) * kS;
  const float* rB = rA + kS;
  float eA0 = 0.f, eA1 = 0.f;
  if (half == 0 && y0 != 0 && (y0 & 31) == 0) {
    const float* bp = bnd + ((size_t)b * 7 + (y0 >> 5) - 1) * kS;
    eA0 = bp[lane]; eA1 = bp[lane + 128];
  }
  float2* a = smA[half];
  a[lane]       = make_float2(rA[lane] + eA0,       rB[lane]);
  a[lane + 128] = make_float2(rA[lane + 128] + eA1, rB[lane + 128]);
  __syncthreads();
  fft256t<-1>(a, smB[half], lane, tw);   // result in smA[half]

  // unpack 4 row-spectra at k=t (t<=128) and transpose-write 32B chunks
  if (t <= 128) {
    int tm = (256 - t) & 255;
    float2 Zk0 = smA[0][t], Zm0 = smA[0][tm];
    float2 Zk1 = smA[1][t], Zm1 = smA[1][tm];
    float4 o0 = make_float4(0.5f * (Zk0.x + Zm0.x), 0.5f * (Zk0.y - Zm0.y),
                            0.5f * (Zk0.y + Zm0.y), 0.5f * (Zm0.x - Zk0.x));
    float4 o1 = make_float4(0.5f * (Zk1.x + Zm1.x), 0.5f * (Zk1.y - Zm1.y),
                            0.5f * (Zk1.y + Zm1.y), 0.5f * (Zm1.x - Zk1.x));
    float4* o = reinterpret_cast<float4*>(FcT + ((size_t)b * kKx + t) * kS + y0);
    o[0] = o0;
    o[1] = o1;
  }
}

__global__ __launch_bounds__(256) void k_fft_cols(float2* __restrict__ FcT,
                                                  const float* __restrict__ defocus) {
  __shared__ float2 sm[4][256];
  __shared__ float2 tw[128];
  const int t = threadIdx.x, half = t >> 7, lane = t & 127;
  build_tw(tw, t);
  const int b = blockIdx.x / 65, kxp = blockIdx.x % 65;
  const int kx = kxp * 2 + half;          // 0..129; 129 is duplicate work
  const int kxr = min(kx, 128);
  float2* col = FcT + ((size_t)b * kKx + kxr) * kS;   // contiguous column
  float2* a = sm[half * 2];
  float2* bb = sm[half * 2 + 1];
  __syncthreads();
  a[lane]       = col[lane];
  a[lane + 128] = col[lane + 128];
  float2* r1 = fft256t<-1>(a, bb, lane, tw);

  // apply real filter H(ky,kx) = G * CTF (defocus-dependent per pose)
  const float D = defocus[b];
  const float fxv = (float)kxr * (1.0f / 256.0f);     // rfftfreq: 0..0.5
  const float fx2 = fxv * fxv;
#pragma unroll
  for (int h = 0; h < 2; ++h) {
    int ky = lane + h * 128;
    float fyv = (float)(ky < 128 ? ky : ky - 256) * (1.0f / 256.0f);
    float s2 = fyv * fyv + fx2;
    float G = __expf(-kGauss * s2);
    float chi = kA1 * D * s2 - kA2 * s2 * s2;
    float sn, cn;
    sincosf(chi, &sn, &cn);
    float H = G * (-(kW1 * sn + kQ0 * cn));
    r1[ky].x *= H;
    r1[ky].y *= H;
  }
  float2* r2 = (r1 == a) ? bb : a;
  float2* res = fft256t<1>(r1, r2, lane, tw);
  if (kx <= 128) {
    col[lane]       = res[lane];
    col[lane + 128] = res[lane + 128];
  }
}

__global__ __launch_bounds__(256) void k_fft_rows_inv(const float2* __restrict__ FcT,
                                                      float* __restrict__ out) {
  __shared__ float2 smA[2][256];
  __shared__ float2 smB[2][256];
  __shared__ float2 smT[130 * 5];          // [k][r], stride 5 to spread banks
  __shared__ float2 tw[128];
  const int t = threadIdx.x, half = t >> 7, lane = t & 127;
  build_tw(tw, t);
  const int b = blockIdx.x >> 6;
  const int y0 = (blockIdx.x & 63) * 4;

  // stage T(k, y0..y0+3), k = 0..128 (transpose read, 32B chunks)
  if (t < 129) {
    const float4* ip =
        reinterpret_cast<const float4*>(FcT + ((size_t)b * kKx + t) * kS + y0);
    float4 w0 = ip[0], w1 = ip[1];
    smT[t * 5 + 0] = make_float2(w0.x, w0.y);
    smT[t * 5 + 1] = make_float2(w0.z, w0.w);
    smT[t * 5 + 2] = make_float2(w1.x, w1.y);
    smT[t * 5 + 3] = make_float2(w1.z, w1.w);
  }
  __syncthreads();

  // build Z(k) = T1(k) + i*T2(k) with Hermitian extension for k>128
  float2* a = smA[half];
  {
    float2 T1 = smT[lane * 5 + 2 * half], T2 = smT[lane * 5 + 2 * half + 1];
    a[lane] = make_float2(T1.x - T2.y, T1.y + T2.x);
    int km = (lane == 0) ? 128 : (128 - lane);
    float2 T1m = smT[km * 5 + 2 * half], T2m = smT[km * 5 + 2 * half + 1];
    a[lane + 128] = (lane == 0)
        ? make_float2(T1m.x - T2m.y, T1m.y + T2m.x)
        : make_float2(T1m.x + T2m.y, -T1m.y + T2m.x);
  }
  __syncthreads();
  float2* res = fft256t<1>(a, smB[half], lane, tw);  // rows y0+2h, y0+2h+1

  float* o0 = out + ((size_t)b * kS + y0 + 2 * half) * kS;
  float* o1 = o0 + kS;
  o0[lane]       = res[lane].x * (1.0f / 65536.0f);
  o0[lane + 128] = res[lane + 128].x * (1.0f / 65536.0f);
  o1[lane]       = res[lane].y * (1.0f / 65536.0f);
  o1[lane + 128] = res[lane + 128].y * (1.0f / 65536.0f);
}

// ---------------------------------------------------------------------------
extern "C" void kernel_launch(void* const* d_in, const int* in_sizes, int n_in,
                              void* d_out, int out_size, void* d_ws, size_t ws_size,
                              hipStream_t stream) {
  const float* c_nma        = (const float*)d_in[0];
  const float* delta_euler  = (const float*)d_in[1];
  const float* delta_shifts = (const float*)d_in[2];
  const float* coords       = (const float*)d_in[3];
  const float* basis_x      = (const float*)d_in[4];
  const float* basis_y      = (const float*)d_in[5];
  const float* basis_z      = (const float*)d_in[6];
  const float* euler_base   = (const float*)d_in[7];
  const float* shifts_base  = (const float*)d_in[8];
  const float* defocus      = (const float*)d_in[9];

  float* out = (float*)d_out;
  float* decoded = out;                                   // B*S*S
  float* bond    = out + (size_t)kB * kS * kS;            // B*(N-1)
  float* angle   = bond + (size_t)kB * (kN - 1);          // B*(N-2)

  char* ws = (char*)d_ws;
  const size_t imgBytes = (size_t)kB * kS * kS * sizeof(float);        // 8 MB
  float*    img    = (float*)ws;                           // [0, 8MB)
  unsigned* xy_bkt = (unsigned*)(ws + imgBytes);           // [8MB, 24MB) dead after k_splat
  float2*   FcT    = (float2*)(ws + imgBytes);             // [8MB, 16.5MB) aliases xy_bkt (after splat)
  int*      gcount = (int*)(ws + imgBytes + (size_t)17 * 1024 * 1024);  // [25MB, +1KB)
  float*    bnd    = (float*)(ws + imgBytes + (size_t)18 * 1024 * 1024);// [26MB, +229KB)

  hipMemsetAsync(gcount, 0, (size_t)kB * 8 * sizeof(int), stream);

  dim3 gd(kNB, kB / kBG);
  k_deform<<<gd, 256, 0, stream>>>(c_nma, delta_euler, delta_shifts, coords,
                                   basis_x, basis_y, basis_z, euler_base,
                                   shifts_base, xy_bkt, gcount, bond, angle);
  k_splat<<<kB * 8, 1024, 0, stream>>>(xy_bkt, gcount, img, bnd);
  k_fft_rows_fwd<<<kB * 64, 256, 0, stream>>>(img, bnd, FcT);
  k_fft_cols<<<kB * 65, 256, 0, stream>>>(FcT, defocus);
  k_fft_rows_inv<<<kB * 64, 256, 0, stream>>>(FcT, decoded);
}

// Round 9
// 75.384 us; speedup vs baseline: 9.3729x; 1.0004x over previous
//
#include <hip/hip_runtime.h>
#include <math.h>

namespace {
constexpr int kB = 32;
constexpr int kN = 100000;
constexpr int kL = 12;
constexpr int kS = 256;
constexpr int kBG = 8;                      // poses per block in deform kernel
constexpr int kWOwn = 62;                   // atoms OWNED per wave (2 shuffle-halo lanes)
constexpr int kTile = 4 * kWOwn;            // 248 atoms owned per 256-thread block
constexpr int kNB = (kN + kTile - 1) / kTile;  // 404 atom-blocks
constexpr int kCap = 16384;                 // per-(pose,band) bucket capacity
constexpr int kKx = 130;                    // stored kx columns (129 used + pad)

constexpr float kGauss = (float)(2.0 * M_PI * M_PI);                         // 2(pi*sigma)^2, sigma=1
constexpr float kA1 = (float)(M_PI * 0.0197);                                // pi*lambda
constexpr float kA2 = (float)(0.5 * M_PI * 2.7e7 * 0.0197 * 0.0197 * 0.0197);// 0.5*pi*Cs*lambda^3
constexpr float kW1 = 0.99498743710661995f;                                  // sqrt(1-Q0^2)
constexpr float kQ0 = 0.1f;
}

// ---------------------------------------------------------------------------
// Zero the 256-int gcount array. Replaces hipMemsetAsync: the blit-engine
// fill node measured 43-45 us in-graph (WRITE_SIZE=1KB dispatches, r6/r7
// profiles); a plain kernel node avoids the engine switch.
// ---------------------------------------------------------------------------
__global__ __launch_bounds__(256) void k_zero(int* __restrict__ gcount) {
  gcount[threadIdx.x] = 0;
}

// ---------------------------------------------------------------------------
// 256-point Stockham radix-2 FFT in LDS with a shared twiddle table.
// 128 lanes per FFT, 8 stages, auto-sorting. Result ends in buffer `a`.
// tw[k] = (cos, sin)(pi*k/128); SIGN=-1 forward, +1 inverse.
// Contains __syncthreads(): all 256 threads of the block must call uniformly.
// ---------------------------------------------------------------------------
template <int SIGN>
__device__ __forceinline__ float2* fft256t(float2* a, float2* b, int lane,
                                           const float2* tw) {
#pragma unroll
  for (int m = 1; m <= 128; m <<= 1) {
    float2 c0 = a[lane];
    float2 c1 = a[lane + 128];
    int jm = lane & ~(m - 1);
    float2 w = tw[jm];
    float c = w.x;
    float s = (SIGN < 0) ? -w.y : w.y;
    float ex = c0.x + c1.x, ey = c0.y + c1.y;
    float dx = c0.x - c1.x, dy = c0.y - c1.y;
    b[lane + jm]     = make_float2(ex, ey);
    b[lane + jm + m] = make_float2(c * dx - s * dy, c * dy + s * dx);
    __syncthreads();
    float2* tp = a; a = b; b = tp;
  }
  return a;  // 8 swaps -> result back in original `a` buffer
}

__device__ __forceinline__ void build_tw(float2* tw, int t) {
  if (t < 128) {
    float s, c;
    sincosf((float)M_PI / 128.0f * (float)t, &s, &c);
    tw[t] = make_float2(c, s);
  }
}

// ---------------------------------------------------------------------------
// Phase A: deformation -> bond, angle, projected (x,y) packed u16.8 into
// per-(pose, 32-row band) compact bucket lists.
// Wave w owns atoms [blk*248 + w*62, +62); all 64 lanes compute (2 halo
// lanes), neighbors p[n+1]/p[n+2] come from __shfl_down -- NO barrier in the
// pose loop and no pt[] LDS. Loads clamp to atom kN-1 (the clamped duplicate
// IS the correct neighbor at the chain end). Batched reservation at the end.
// ---------------------------------------------------------------------------
__global__ __launch_bounds__(256) void k_deform(
    const float* __restrict__ c_nma, const float* __restrict__ delta_euler,
    const float* __restrict__ delta_shifts, const float* __restrict__ coords,
    const float* __restrict__ basis_x, const float* __restrict__ basis_y,
    const float* __restrict__ basis_z, const float* __restrict__ euler_base,
    const float* __restrict__ shifts_base,
    unsigned* __restrict__ xy_bkt, int* __restrict__ gcount,
    float* __restrict__ bond, float* __restrict__ angle) {
  __shared__ float cn_s[kBG][kL];
  __shared__ float rsh_s[kBG][8];
  __shared__ int bcnt[kBG][8];
  __shared__ int bbase[kBG][8];

  const int t = threadIdx.x;
  const int wave = t >> 6, lane = t & 63;
  const int bg = blockIdx.y * kBG;
  const int n = blockIdx.x * kTile + wave * kWOwn + lane;
  const bool owner = (lane < kWOwn) && (n < kN);
  const int nc = min(n, kN - 1);

  if (t < kBG * kL) cn_s[t / kL][t % kL] = c_nma[(bg + t / kL) * kL + (t % kL)];
  if (t < kBG) {
    int b = bg + t;
    float rot  = euler_base[b * 3 + 0] + delta_euler[b * 3 + 0];
    float tilt = euler_base[b * 3 + 1] + delta_euler[b * 3 + 1];
    float psi  = euler_base[b * 3 + 2] + delta_euler[b * 3 + 2];
    float ca = cosf(rot), sa = sinf(rot);
    float cb = cosf(tilt), sb = sinf(tilt);
    float cg = cosf(psi), sg = sinf(psi);
    rsh_s[t][0] = cg * cb * ca - sg * sa;
    rsh_s[t][1] = cg * cb * sa + sg * ca;
    rsh_s[t][2] = -cg * sb;
    rsh_s[t][3] = -sg * cb * ca - cg * sa;
    rsh_s[t][4] = -sg * cb * sa + cg * ca;
    rsh_s[t][5] = sg * sb;
    rsh_s[t][6] = shifts_base[b * 2 + 0] + delta_shifts[b * 2 + 0] + 128.0f;
    rsh_s[t][7] = shifts_base[b * 2 + 1] + delta_shifts[b * 2 + 1] + 128.0f;
  }
  if (t < kBG * 8) bcnt[t >> 3][t & 7] = 0;

  const float cx = coords[nc * 3 + 0];
  const float cy = coords[nc * 3 + 1];
  const float cz = coords[nc * 3 + 2];
  float bx[kL], by[kL], bz[kL];
  {
    const float4* px4 = reinterpret_cast<const float4*>(basis_x + (size_t)nc * kL);
    const float4* py4 = reinterpret_cast<const float4*>(basis_y + (size_t)nc * kL);
    const float4* pz4 = reinterpret_cast<const float4*>(basis_z + (size_t)nc * kL);
#pragma unroll
    for (int q = 0; q < 3; ++q) {
      float4 vx = px4[q], vy = py4[q], vz = pz4[q];
      bx[q * 4 + 0] = vx.x; bx[q * 4 + 1] = vx.y; bx[q * 4 + 2] = vx.z; bx[q * 4 + 3] = vx.w;
      by[q * 4 + 0] = vy.x; by[q * 4 + 1] = vy.y; by[q * 4 + 2] = vy.z; by[q * 4 + 3] = vy.w;
      bz[q * 4 + 0] = vz.x; bz[q * 4 + 1] = vz.y; bz[q * 4 + 2] = vz.z; bz[q * 4 + 3] = vz.w;
    }
  }
  __syncthreads();

  unsigned ureg[kBG];   // packed (y<<16)|x per pose
  unsigned meta[kBG];   // (rank<<3)|band per pose

#pragma unroll
  for (int bi = 0; bi < kBG; ++bi) {
    const int b = bg + bi;
    float px = cx, py = cy, pz = cz;
#pragma unroll
    for (int l = 0; l < kL; ++l) {
      float cc = cn_s[bi][l];
      px = fmaf(cc, bx[l], px);
      py = fmaf(cc, by[l], py);
      pz = fmaf(cc, bz[l], pz);
    }
    // neighbors via wave shuffles (lanes 62/63 receive garbage; non-owners)
    float p1x = __shfl_down(px, 1), p1y = __shfl_down(py, 1), p1z = __shfl_down(pz, 1);
    float p2x = __shfl_down(p1x, 1), p2y = __shfl_down(p1y, 1), p2z = __shfl_down(p1z, 1);

    ureg[bi] = 0; meta[bi] = 0;
    if (owner) {
      // projection; quantize to u16.8 fixed point (floor), pack (y<<16)|x
      float xr = fmaf(rsh_s[bi][0], px, fmaf(rsh_s[bi][1], py, fmaf(rsh_s[bi][2], pz, rsh_s[bi][6])));
      float yr = fmaf(rsh_s[bi][3], px, fmaf(rsh_s[bi][4], py, fmaf(rsh_s[bi][5], pz, rsh_s[bi][7])));
      xr = fminf(fmaxf(xr, 0.0f), 254.999f);
      yr = fminf(fmaxf(yr, 0.0f), 254.999f);
      unsigned xf = (unsigned)(xr * 256.0f);   // <= 65279 -> x0 <= 254
      unsigned yf = (unsigned)(yr * 256.0f);
      unsigned band = yf >> 13;                // row>>5, 0..7
      int rank = atomicAdd(&bcnt[bi][band], 1);
      ureg[bi] = (yf << 16) | xf;
      meta[bi] = ((unsigned)rank << 3) | band;
      // bond length at n (atoms n, n+1)
      if (n < kN - 1) {
        float dx = p1x - px, dy = p1y - py, dz = p1z - pz;
        bond[(size_t)b * (kN - 1) + n] =
            sqrtf(fmaf(dx, dx, fmaf(dy, dy, fmaf(dz, dz, 1e-12f))));
      }
      // angle at interior atom n+1 (atoms n, n+1, n+2); fast acos
      if (n < kN - 2) {
        float ux = px - p1x, uy = py - p1y, uz = pz - p1z;
        float vx = p2x - p1x, vy = p2y - p1y, vz = p2z - p1z;
        float uu = fmaf(ux, ux, fmaf(uy, uy, uz * uz));
        float vv = fmaf(vx, vx, fmaf(vy, vy, vz * vz));
        float uv = fmaf(ux, vx, fmaf(uy, vy, uz * vz));
        float cosang = uv * rsqrtf(uu * vv);
        cosang = fminf(fmaxf(cosang, -0.9999f), 0.9999f);
        float ax = fabsf(cosang);
        float rt = sqrtf(1.0f - ax);
        float pp = fmaf(fmaf(fmaf(-0.0187293f, ax, 0.0742610f), ax, -0.2121144f),
                        ax, 1.5707288f);
        float res = rt * pp;
        angle[(size_t)b * (kN - 2) + n] = (cosang >= 0.f) ? res : (float)M_PI - res;
      }
    }
  }
  __syncthreads();
  if (t < kBG * 8) {
    int po = t >> 3, bandx = t & 7;
    int c = bcnt[po][bandx];
    bbase[po][bandx] = c ? atomicAdd(&gcount[(bg + po) * 8 + bandx], c) : 0;
  }
  __syncthreads();
#pragma unroll
  for (int bi = 0; bi < kBG; ++bi) {
    if (owner) {
      unsigned band = meta[bi] & 7;
      int pos = bbase[bi][band] + (int)(meta[bi] >> 3);
      if (pos < kCap) xy_bkt[((size_t)(bg + bi) * 8 + band) * kCap + pos] = ureg[bi];
    }
  }
}

// ---------------------------------------------------------------------------
// Phase B: bilinear splat from per-(pose,band) compact lists into a 33x256
// INTEGER (u18.14) LDS tile via native ds_add_u32. ALL outputs are plain
// stores: rows 0..31 -> img; r=32 overflow -> bnd[b][band][256] (added back
// at FFT-load time). img needs NO zero-init. grid: 32*8, 1024 threads.
// ---------------------------------------------------------------------------
__global__ __launch_bounds__(1024) void k_splat(const unsigned* __restrict__ xy_bkt,
                                                const int* __restrict__ gcount,
                                                float* __restrict__ img,
                                                float* __restrict__ bnd) {
  __shared__ unsigned tile[33 * 256];
  const int t = threadIdx.x;
  const int b = blockIdx.x >> 3;
  const int band = blockIdx.x & 7;
  const int r0 = band * 32;
  for (int i = t; i < 33 * 256; i += 1024) tile[i] = 0u;
  __syncthreads();

  const int c = min(gcount[b * 8 + band], kCap);
  const unsigned* seg = xy_bkt + ((size_t)b * 8 + band) * kCap;

  auto splat1 = [&](unsigned u) {
    int yf = (int)(u >> 16);
    int xf = (int)(u & 0xFFFFu);
    int ry = (yf >> 8) - r0;                 // guaranteed 0..31 by bucketing
    int x0 = xf >> 8;
    int fx = xf & 255, fy = yf & 255;        // u0.8 fractions
    int gx = 256 - fx, gy = 256 - fy;
    int base = ry * 256 + x0;
    // w * 2^14 = (w8a * w8b + 2) >> 2  (round-to-nearest-ish)
    atomicAdd(&tile[base],       (unsigned)((gx * gy + 2) >> 2));
    atomicAdd(&tile[base + 1],   (unsigned)((fx * gy + 2) >> 2));
    atomicAdd(&tile[base + 256], (unsigned)((gx * fy + 2) >> 2));
    atomicAdd(&tile[base + 257], (unsigned)((fx * fy + 2) >> 2));
  };

  const int c4 = c & ~3;
  const uint4* seg4 = reinterpret_cast<const uint4*>(seg);
  for (int i4 = t; i4 * 4 < c4; i4 += 1024) {
    uint4 q = seg4[i4];
    splat1(q.x); splat1(q.y); splat1(q.z); splat1(q.w);
  }
  for (int i = c4 + t; i < c; i += 1024) splat1(seg[i]);
  __syncthreads();

  const int col = t & 255;
  for (int r = (t >> 8); r < 33; r += 4) {
    float v = (float)tile[r * 256 + col] * (1.0f / 16384.0f);
    if (r < 32)          img[((size_t)b * kS + r0 + r) * kS + col] = v;
    else if (band < 7)   bnd[((size_t)b * 7 + band) * kS + col] = v;
  }
}

// ---------------------------------------------------------------------------
// FFT passes with real-FFT packing (2 real rows per complex FFT) and
// Hermitian-reduced spectrum: only kx = 0..128 stored, TRANSPOSED:
// FcT[b][kx][y], kx-stride kKx=130.
// ---------------------------------------------------------------------------
__global__ __launch_bounds__(256) void k_fft_rows_fwd(const float* __restrict__ img,
                                                      const float* __restrict__ bnd,
                                                      float2* __restrict__ FcT) {
  __shared__ float2 smA[2][256];
  __shared__ float2 smB[2][256];
  __shared__ float2 tw[128];
  const int t = threadIdx.x, half = t >> 7, lane = t & 127;
  build_tw(tw, t);
  const int b = blockIdx.x >> 6;
  const int y0 = (blockIdx.x & 63) * 4;

  // pack rows (y0+2h, y0+2h+1) as re+i*im; add band-overflow to rows %32==0
  const float* rA = img + ((size_t)b * kS + y0 + 2 * half) * kS;
  const float* rB = rA + kS;
  float eA0 = 0.f, eA1 = 0.f;
  if (half == 0 && y0 != 0 && (y0 & 31) == 0) {
    const float* bp = bnd + ((size_t)b * 7 + (y0 >> 5) - 1) * kS;
    eA0 = bp[lane]; eA1 = bp[lane + 128];
  }
  float2* a = smA[half];
  a[lane]       = make_float2(rA[lane] + eA0,       rB[lane]);
  a[lane + 128] = make_float2(rA[lane + 128] + eA1, rB[lane + 128]);
  __syncthreads();
  fft256t<-1>(a, smB[half], lane, tw);   // result in smA[half]

  // unpack 4 row-spectra at k=t (t<=128) and transpose-write 32B chunks
  if (t <= 128) {
    int tm = (256 - t) & 255;
    float2 Zk0 = smA[0][t], Zm0 = smA[0][tm];
    float2 Zk1 = smA[1][t], Zm1 = smA[1][tm];
    float4 o0 = make_float4(0.5f * (Zk0.x + Zm0.x), 0.5f * (Zk0.y - Zm0.y),
                            0.5f * (Zk0.y + Zm0.y), 0.5f * (Zm0.x - Zk0.x));
    float4 o1 = make_float4(0.5f * (Zk1.x + Zm1.x), 0.5f * (Zk1.y - Zm1.y),
                            0.5f * (Zk1.y + Zm1.y), 0.5f * (Zm1.x - Zk1.x));
    float4* o = reinterpret_cast<float4*>(FcT + ((size_t)b * kKx + t) * kS + y0);
    o[0] = o0;
    o[1] = o1;
  }
}

__global__ __launch_bounds__(256) void k_fft_cols(float2* __restrict__ FcT,
                                                  const float* __restrict__ defocus) {
  __shared__ float2 sm[4][256];
  __shared__ float2 tw[128];
  const int t = threadIdx.x, half = t >> 7, lane = t & 127;
  build_tw(tw, t);
  const int b = blockIdx.x / 65, kxp = blockIdx.x % 65;
  const int kx = kxp * 2 + half;          // 0..129; 129 is duplicate work
  const int kxr = min(kx, 128);
  float2* col = FcT + ((size_t)b * kKx + kxr) * kS;   // contiguous column
  float2* a = sm[half * 2];
  float2* bb = sm[half * 2 + 1];
  __syncthreads();
  a[lane]       = col[lane];
  a[lane + 128] = col[lane + 128];
  float2* r1 = fft256t<-1>(a, bb, lane, tw);

  // apply real filter H(ky,kx) = G * CTF (defocus-dependent per pose)
  const float D = defocus[b];
  const float fxv = (float)kxr * (1.0f / 256.0f);     // rfftfreq: 0..0.5
  const float fx2 = fxv * fxv;
#pragma unroll
  for (int h = 0; h < 2; ++h) {
    int ky = lane + h * 128;
    float fyv = (float)(ky < 128 ? ky : ky - 256) * (1.0f / 256.0f);
    float s2 = fyv * fyv + fx2;
    float G = __expf(-kGauss * s2);
    float chi = kA1 * D * s2 - kA2 * s2 * s2;
    float sn, cn;
    sincosf(chi, &sn, &cn);
    float H = G * (-(kW1 * sn + kQ0 * cn));
    r1[ky].x *= H;
    r1[ky].y *= H;
  }
  float2* r2 = (r1 == a) ? bb : a;
  float2* res = fft256t<1>(r1, r2, lane, tw);
  if (kx <= 128) {
    col[lane]       = res[lane];
    col[lane + 128] = res[lane + 128];
  }
}

__global__ __launch_bounds__(256) void k_fft_rows_inv(const float2* __restrict__ FcT,
                                                      float* __restrict__ out) {
  __shared__ float2 smA[2][256];
  __shared__ float2 smB[2][256];
  __shared__ float2 smT[130 * 5];          // [k][r], stride 5 to spread banks
  __shared__ float2 tw[128];
  const int t = threadIdx.x, half = t >> 7, lane = t & 127;
  build_tw(tw, t);
  const int b = blockIdx.x >> 6;
  const int y0 = (blockIdx.x & 63) * 4;

  // stage T(k, y0..y0+3), k = 0..128 (transpose read, 32B chunks)
  if (t < 129) {
    const float4* ip =
        reinterpret_cast<const float4*>(FcT + ((size_t)b * kKx + t) * kS + y0);
    float4 w0 = ip[0], w1 = ip[1];
    smT[t * 5 + 0] = make_float2(w0.x, w0.y);
    smT[t * 5 + 1] = make_float2(w0.z, w0.w);
    smT[t * 5 + 2] = make_float2(w1.x, w1.y);
    smT[t * 5 + 3] = make_float2(w1.z, w1.w);
  }
  __syncthreads();

  // build Z(k) = T1(k) + i*T2(k) with Hermitian extension for k>128
  float2* a = smA[half];
  {
    float2 T1 = smT[lane * 5 + 2 * half], T2 = smT[lane * 5 + 2 * half + 1];
    a[lane] = make_float2(T1.x - T2.y, T1.y + T2.x);
    int km = (lane == 0) ? 128 : (128 - lane);
    float2 T1m = smT[km * 5 + 2 * half], T2m = smT[km * 5 + 2 * half + 1];
    a[lane + 128] = (lane == 0)
        ? make_float2(T1m.x - T2m.y, T1m.y + T2m.x)
        : make_float2(T1m.x + T2m.y, -T1m.y + T2m.x);
  }
  __syncthreads();
  float2* res = fft256t<1>(a, smB[half], lane, tw);  // rows y0+2h, y0+2h+1

  float* o0 = out + ((size_t)b * kS + y0 + 2 * half) * kS;
  float* o1 = o0 + kS;
  o0[lane]       = res[lane].x * (1.0f / 65536.0f);
  o0[lane + 128] = res[lane + 128].x * (1.0f / 65536.0f);
  o1[lane]       = res[lane].y * (1.0f / 65536.0f);
  o1[lane + 128] = res[lane + 128].y * (1.0f / 65536.0f);
}

// ---------------------------------------------------------------------------
extern "C" void kernel_launch(void* const* d_in, const int* in_sizes, int n_in,
                              void* d_out, int out_size, void* d_ws, size_t ws_size,
                              hipStream_t stream) {
  const float* c_nma        = (const float*)d_in[0];
  const float* delta_euler  = (const float*)d_in[1];
  const float* delta_shifts = (const float*)d_in[2];
  const float* coords       = (const float*)d_in[3];
  const float* basis_x      = (const float*)d_in[4];
  const float* basis_y      = (const float*)d_in[5];
  const float* basis_z      = (const float*)d_in[6];
  const float* euler_base   = (const float*)d_in[7];
  const float* shifts_base  = (const float*)d_in[8];
  const float* defocus      = (const float*)d_in[9];

  float* out = (float*)d_out;
  float* decoded = out;                                   // B*S*S
  float* bond    = out + (size_t)kB * kS * kS;            // B*(N-1)
  float* angle   = bond + (size_t)kB * (kN - 1);          // B*(N-2)

  char* ws = (char*)d_ws;
  const size_t imgBytes = (size_t)kB * kS * kS * sizeof(float);        // 8 MB
  float*    img    = (float*)ws;                           // [0, 8MB)
  unsigned* xy_bkt = (unsigned*)(ws + imgBytes);           // [8MB, 24MB) dead after k_splat
  float2*   FcT    = (float2*)(ws + imgBytes);             // [8MB, 16.5MB) aliases xy_bkt (after splat)
  int*      gcount = (int*)(ws + imgBytes + (size_t)17 * 1024 * 1024);  // [25MB, +1KB)
  float*    bnd    = (float*)(ws + imgBytes + (size_t)18 * 1024 * 1024);// [26MB, +229KB)

  k_zero<<<1, 256, 0, stream>>>(gcount);

  dim3 gd(kNB, kB / kBG);
  k_deform<<<gd, 256, 0, stream>>>(c_nma, delta_euler, delta_shifts, coords,
                                   basis_x, basis_y, basis_z, euler_base,
                                   shifts_base, xy_bkt, gcount, bond, angle);
  k_splat<<<kB * 8, 1024, 0, stream>>>(xy_bkt, gcount, img, bnd);
  k_fft_rows_fwd<<<kB * 64, 256, 0, stream>>>(img, bnd, FcT);
  k_fft_cols<<<kB * 65, 256, 0, stream>>>(FcT, defocus);
  k_fft_rows_inv<<<kB * 64, 256, 0, stream>>>(FcT, decoded);
}